// Round 4
// baseline (1252.527 us; speedup 1.0000x reference)
//
#include <hip/hip_runtime.h>
#include <hip/hip_bf16.h>
#include <stdint.h>

#define BF16 __hip_bfloat16

typedef __attribute__((ext_vector_type(8))) short short8;
typedef __attribute__((ext_vector_type(2))) short short2v;
typedef __attribute__((ext_vector_type(4))) float floatx4;

typedef const __attribute__((address_space(1))) void* gas_cvp;
typedef __attribute__((address_space(3))) void* las_vp;

__device__ __forceinline__ float bf2f(BF16 v) { return __bfloat162float(v); }
__device__ __forceinline__ BF16 f2bf(float v) { return __float2bfloat16(v); }

// ---------------------------------------------------------------------------
// Weight fp32 [K,N] -> bf16 transposed [N,K]
// ---------------------------------------------------------------------------
__global__ __launch_bounds__(256) void wtrans(const float* __restrict__ W,
                                              BF16* __restrict__ Wt, int K, int N) {
    __shared__ float t[32][33];
    int k0 = blockIdx.x * 32, n0 = blockIdx.y * 32;
    int tx = threadIdx.x & 31, ty = threadIdx.x >> 5;  // ty 0..7
#pragma unroll
    for (int i = 0; i < 32; i += 8) t[ty + i][tx] = W[(size_t)(k0 + ty + i) * N + n0 + tx];
    __syncthreads();
#pragma unroll
    for (int i = 0; i < 32; i += 8)
        Wt[(size_t)(n0 + ty + i) * K + k0 + tx] = f2bf(t[tx][ty + i]);
}

// ---------------------------------------------------------------------------
// LayerNorm over 768 cols, block=256.
// ---------------------------------------------------------------------------
template <int MODE>
__global__ __launch_bounds__(256) void ln_kernel(const float* __restrict__ src0,
                                                 const float* __restrict__ src1,
                                                 const BF16* __restrict__ srcb,
                                                 const float* __restrict__ g,
                                                 const float* __restrict__ bta,
                                                 BF16* __restrict__ dst_bf,
                                                 float* __restrict__ dst_f) {
    const int r = blockIdx.x, tid = threadIdx.x;
    float x0, x1, x2;
    if (MODE == 3) {
        const BF16* src = srcb + (size_t)r * 197 * 768;
        x0 = bf2f(src[tid]); x1 = bf2f(src[tid + 256]); x2 = bf2f(src[tid + 512]);
    } else {
        const float* src;
        if (MODE == 0) {
            int b = r / 3136, rr = r - b * 3136;
            src = src0 + ((size_t)b * 3137 + 1 + rr) * 768;
        } else if (MODE == 1) {
            int bt = r / 197, j = r - bt * 197;
            int b = bt >> 4, t = bt & 15;
            if (j == 0) src = src0 + (size_t)b * 3137 * 768;
            else        src = src1 + ((size_t)(b * 3137 + 1) + (size_t)(j - 1) * 16 + t) * 768;
        } else {
            src = src0 + (size_t)r * 768;
        }
        x0 = src[tid]; x1 = src[tid + 256]; x2 = src[tid + 512];
    }
    float s = x0 + x1 + x2;
    float ss = x0 * x0 + x1 * x1 + x2 * x2;
    __shared__ float red[8];
#pragma unroll
    for (int o = 32; o > 0; o >>= 1) { s += __shfl_down(s, o); ss += __shfl_down(ss, o); }
    if ((tid & 63) == 0) { red[tid >> 6] = s; red[4 + (tid >> 6)] = ss; }
    __syncthreads();
    s = red[0] + red[1] + red[2] + red[3];
    ss = red[4] + red[5] + red[6] + red[7];
    const float mu = s * (1.0f / 768.0f);
    const float var = ss * (1.0f / 768.0f) - mu * mu;
    const float rstd = rsqrtf(var + 1e-5f);
#pragma unroll
    for (int i = 0; i < 3; ++i) {
        int c = tid + i * 256;
        float xv = (i == 0) ? x0 : (i == 1) ? x1 : x2;
        float y = (xv - mu) * rstd * g[c] + bta[c];
        if (MODE == 3) dst_f[(size_t)r * 768 + c] = y;
        else           dst_bf[(size_t)r * 768 + c] = f2bf(y);
    }
}

// ---------------------------------------------------------------------------
// 128x128 bf16 GEMM (m97 structure) — kept for small grids (p8/p4 RMW modes).
// ---------------------------------------------------------------------------
template <int AMAP, int OMODE>
__global__ __launch_bounds__(256) void gemm_bf16(const BF16* __restrict__ A,
                                                 const BF16* __restrict__ Bt,
                                                 const float* __restrict__ bias,
                                                 const void* res,
                                                 void* Cout,
                                                 int M, int N, int K) {
    __shared__ BF16 Al[128 * 64];
    __shared__ BF16 Bl[128 * 64];
    const int tid = threadIdx.x;
    const int lane = tid & 63;
    const int w = tid >> 6;

    const int gx = gridDim.x;
    const int nwg = gx * (int)gridDim.y;
    const int orig = (int)blockIdx.y * gx + (int)blockIdx.x;
    const int xcd = orig & 7;
    const int idx = orig >> 3;
    const int q8 = nwg >> 3, r8 = nwg & 7;
    const int wgid = (xcd < r8 ? xcd * (q8 + 1) : r8 * (q8 + 1) + (xcd - r8) * q8) + idx;
    const int bn0 = (wgid % gx) * 128;
    const int bm0 = (wgid / gx) * 128;

    const BF16* gsrc[8];
    BF16* ldst[8];
    const int rin = lane >> 3;
    const int kblk = (lane & 7) ^ rin;
#pragma unroll
    for (int j = 0; j < 8; ++j) {
        int c = w * 8 + j;
        if (c < 16) {
            int gr = bm0 + c * 8 + rin;
            if (gr > M - 1) gr = M - 1;
            if (AMAP == 1) gr = (gr >> 3) * 16 + 8 + (gr & 7);
            if (AMAP == 2) gr = (gr >> 2) * 16 + 12 + (gr & 3);
            gsrc[j] = A + (size_t)gr * K + kblk * 8;
            ldst[j] = Al + c * 512;
        } else {
            int gn = bn0 + (c - 16) * 8 + rin;
            gsrc[j] = Bt + (size_t)gn * K + kblk * 8;
            ldst[j] = Bl + (c - 16) * 512;
        }
    }

    const int wm = (w & 1) * 64;
    const int wn = (w >> 1) * 64;
    const int fr = lane & 15;
    const int fq = lane >> 4;
    const int sw = fr & 7;
    const int o0 = (fq ^ sw) * 8;
    const int o1 = ((fq + 4) ^ sw) * 8;
    const BF16* pa[4];
    const BF16* pb[4];
#pragma unroll
    for (int t = 0; t < 4; ++t) {
        pa[t] = Al + (wm + t * 16 + fr) * 64;
        pb[t] = Bl + (wn + t * 16 + fr) * 64;
    }

    floatx4 acc[4][4];
#pragma unroll
    for (int i = 0; i < 4; ++i)
#pragma unroll
        for (int j = 0; j < 4; ++j) acc[i][j] = (floatx4){0.f, 0.f, 0.f, 0.f};

    for (int k0 = 0; k0 < K; k0 += 64) {
#pragma unroll
        for (int j = 0; j < 8; ++j) {
            __builtin_amdgcn_global_load_lds((gas_cvp)gsrc[j], (las_vp)ldst[j], 16, 0, 0);
            gsrc[j] += 64;
        }
        __syncthreads();
        {
            short8 af[4], bfr[4];
#pragma unroll
            for (int t = 0; t < 4; ++t) {
                af[t] = *(const short8*)(pa[t] + o0);
                bfr[t] = *(const short8*)(pb[t] + o0);
            }
#pragma unroll
            for (int mt = 0; mt < 4; ++mt)
#pragma unroll
                for (int nt = 0; nt < 4; ++nt)
                    acc[mt][nt] = __builtin_amdgcn_mfma_f32_16x16x32_bf16(af[mt], bfr[nt], acc[mt][nt], 0, 0, 0);
#pragma unroll
            for (int t = 0; t < 4; ++t) {
                af[t] = *(const short8*)(pa[t] + o1);
                bfr[t] = *(const short8*)(pb[t] + o1);
            }
#pragma unroll
            for (int mt = 0; mt < 4; ++mt)
#pragma unroll
                for (int nt = 0; nt < 4; ++nt)
                    acc[mt][nt] = __builtin_amdgcn_mfma_f32_16x16x32_bf16(af[mt], bfr[nt], acc[mt][nt], 0, 0, 0);
        }
        __syncthreads();
    }

#pragma unroll
    for (int mt = 0; mt < 4; ++mt) {
#pragma unroll
        for (int nt = 0; nt < 4; ++nt) {
            const int gcol = bn0 + wn + nt * 16 + fr;
#pragma unroll
            for (int r = 0; r < 4; ++r) {
                const int grow = bm0 + wm + mt * 16 + fq * 4 + r;
                if (grow < M) {
                    float v = acc[mt][nt][r];
                    if (OMODE != 0 && OMODE != 8) v += bias[gcol];
                    if (OMODE == 0 || OMODE == 1) {
                        ((BF16*)Cout)[(size_t)grow * N + gcol] = f2bf(v);
                    } else if (OMODE == 2) {
                        int t8 = grow & 7;
                        int rr = (grow >> 3) * 16 + 8 + t8;
                        float w8 = (t8 < 4) ? 0.5f : 0.25f;
                        BF16* R = (BF16*)Cout;
                        size_t o = (size_t)rr * 768 + gcol;
                        R[o] = f2bf(0.5f * bf2f(R[o]) + w8 * v);
                    } else if (OMODE == 3) {
                        int t4 = grow & 3;
                        int rr = (grow >> 2) * 16 + 12 + t4;
                        BF16* R = (BF16*)Cout;
                        size_t o = (size_t)rr * 768 + gcol;
                        R[o] = f2bf(bf2f(R[o]) + 0.25f * v);
                    } else if (OMODE == 4) {
                        int b = grow / 3136;
                        size_t xrow = (size_t)b * 3137 + 1 + (grow - b * 3136);
                        ((float*)Cout)[xrow * 768 + gcol] =
                            v + ((const float*)res)[xrow * 768 + gcol];
                    } else if (OMODE == 6) {
                        float u = v * (0.7978845608f + 0.0356774081f * v * v);
                        v = v / (1.0f + __expf(-2.0f * u));
                        ((BF16*)Cout)[(size_t)grow * N + gcol] = f2bf(v);
                    } else {  // 7, 8
                        v += ((const float*)res)[(size_t)grow * N + gcol];
                        ((float*)Cout)[(size_t)grow * N + gcol] = v;
                    }
                }
            }
        }
    }
}

// ---------------------------------------------------------------------------
// Ring-3 counted-vmcnt bf16 GEMM (T3/T4). BM=256, BN=128, BK=64, 8 waves
// (4M x 2N, each wave 64x64 out). LDS = 3 ring buffers x 48 KB (A 256x64 +
// B 128x64, bf16) = 144 KB -> 1 block/CU.
// Schedule per K-tile t (ONE barrier, counted vmcnt, never 0 mid-loop):
//   vmcnt(6)   // tile t's 6 loads done; tile t+1's 6 still in flight
//   s_barrier  // all waves' tile-t loads visible; buf (t+2)%3 free
//   stage tile t+2 -> buf (t+2)%3   (6 x global_load_lds, 2-tile latency cover)
//   16 ds_read_b128 + 32 MFMA from buf t%3 (setprio around MFMA clusters)
// Swizzle: st_16x32 involution phys_col = col ^ ((row&7)<<4) applied on the
// pre-swizzled GLOBAL source (LDS dest linear, rule #21) and on reads;
// proven conflict-free in round 3 (SQ_LDS_BANK_CONFLICT = 0).
// ---------------------------------------------------------------------------
template <int AMAP, int OMODE>
__global__ __launch_bounds__(512, 2) void gemm_ring(const BF16* __restrict__ A,
                                                    const BF16* __restrict__ Bt,
                                                    const float* __restrict__ bias,
                                                    const void* res,
                                                    void* Cout,
                                                    int M, int N, int K) {
    __shared__ BF16 ring[3][24576];   // 48 KB each: A region [0,32768)B, B region [32768,49152)B
    const int tid = threadIdx.x;
    const int lane = tid & 63;
    const int w = tid >> 6;           // 0..7
    const int wm = w >> 1, wn = w & 1;

    // XCD-chunked bijective swizzle (8 XCDs)
    const int gx = gridDim.x;
    const int nwg = gx * (int)gridDim.y;
    const int orig = (int)blockIdx.y * gx + (int)blockIdx.x;
    const int xcd = orig & 7, sidx = orig >> 3;
    const int q8 = nwg >> 3, r8 = nwg & 7;
    const int wgid = (xcd < r8 ? xcd * (q8 + 1) : r8 * (q8 + 1) + (xcd - r8) * q8) + sidx;
    const int bn0 = (wgid % gx) * 128;
    const int bm0 = (wgid / gx) * 256;

    // staging: 6 chunks of 8 KB per tile (4 A + 2 B); thread -> 16 B at
    // buffer offset lofs[j]; global source pre-swizzled.
    const char* gsrc[6];
    int lofs[6];
#pragma unroll
    for (int j = 0; j < 6; ++j) {
        const int base = (j < 4) ? j * 8192 : 32768 + (j - 4) * 8192;
        const int L = base + w * 1024 + lane * 16;
        lofs[j] = L;
        const int rl = (j < 4) ? (L >> 7) : ((L - 32768) >> 7);   // row in region
        const int cb = (L & 127) ^ ((rl & 7) << 4);               // pre-swizzled col byte
        if (j < 4) {
            int gr = bm0 + rl;
            if (gr > M - 1) gr = M - 1;
            if (AMAP == 1) gr = (gr >> 3) * 16 + 8 + (gr & 7);
            if (AMAP == 2) gr = (gr >> 2) * 16 + 12 + (gr & 3);
            gsrc[j] = (const char*)A + (size_t)gr * (size_t)(K * 2) + cb;
        } else {
            gsrc[j] = (const char*)Bt + (size_t)(bn0 + rl) * (size_t)(K * 2) + cb;
        }
    }

    const int fr = lane & 15, fq = lane >> 4;
    const int xm = (fr & 7) << 4;            // fragment rows ≡ fr (mod 16) -> row&7 = fr&7
    const int cx0 = (fq * 16) ^ xm;          // phys col byte, k-half 0
    const int cx1 = (fq * 16 + 64) ^ xm;     // phys col byte, k-half 1
    const int aOff = (wm * 64 + fr) * 128;           // A frag row byte offset
    const int bOff = 32768 + (wn * 64 + fr) * 128;   // B frag row byte offset

    floatx4 acc[4][4];
#pragma unroll
    for (int i = 0; i < 4; ++i)
#pragma unroll
        for (int j = 0; j < 4; ++j) acc[i][j] = (floatx4){0.f, 0.f, 0.f, 0.f};

    char* const ringbase = (char*)&ring[0][0];

    // prologue: stage tiles 0 and 1
#pragma unroll
    for (int p = 0; p < 2; ++p) {
#pragma unroll
        for (int j = 0; j < 6; ++j) {
            __builtin_amdgcn_global_load_lds((gas_cvp)gsrc[j],
                                             (las_vp)(ringbase + p * 49152 + lofs[j]), 16, 0, 0);
            gsrc[j] += 128;
        }
    }

#define LDA8(mt, kk) (*(const short8*)(Ab + aOff + (mt) * 2048 + ((kk) ? cx1 : cx0)))
#define LDB8(nt, kk) (*(const short8*)(Ab + bOff + (nt) * 2048 + ((kk) ? cx1 : cx0)))

    const int NT = K >> 6;
    int cur = 0, sb = 2;
    for (int t = 0; t < NT; ++t) {
        if (t < NT - 1) asm volatile("s_waitcnt vmcnt(6)" ::: "memory");
        else            asm volatile("s_waitcnt vmcnt(0)" ::: "memory");
        asm volatile("s_barrier" ::: "memory");
        if (t + 2 < NT) {
            char* dst = ringbase + sb * 49152;
#pragma unroll
            for (int j = 0; j < 6; ++j) {
                __builtin_amdgcn_global_load_lds((gas_cvp)gsrc[j], (las_vp)(dst + lofs[j]), 16, 0, 0);
                gsrc[j] += 128;
            }
        }
        const char* Ab = ringbase + cur * 49152;
        {
            short8 a0, a1, a2, a3, b0, b1, b2, b3;
            // k-half 0
            b0 = LDB8(0, 0); b1 = LDB8(1, 0); b2 = LDB8(2, 0); b3 = LDB8(3, 0);
            a0 = LDA8(0, 0); a1 = LDA8(1, 0); a2 = LDA8(2, 0); a3 = LDA8(3, 0);
            __builtin_amdgcn_s_setprio(1);
            acc[0][0] = __builtin_amdgcn_mfma_f32_16x16x32_bf16(a0, b0, acc[0][0], 0, 0, 0);
            acc[0][1] = __builtin_amdgcn_mfma_f32_16x16x32_bf16(a0, b1, acc[0][1], 0, 0, 0);
            acc[0][2] = __builtin_amdgcn_mfma_f32_16x16x32_bf16(a0, b2, acc[0][2], 0, 0, 0);
            acc[0][3] = __builtin_amdgcn_mfma_f32_16x16x32_bf16(a0, b3, acc[0][3], 0, 0, 0);
            acc[1][0] = __builtin_amdgcn_mfma_f32_16x16x32_bf16(a1, b0, acc[1][0], 0, 0, 0);
            acc[1][1] = __builtin_amdgcn_mfma_f32_16x16x32_bf16(a1, b1, acc[1][1], 0, 0, 0);
            acc[1][2] = __builtin_amdgcn_mfma_f32_16x16x32_bf16(a1, b2, acc[1][2], 0, 0, 0);
            acc[1][3] = __builtin_amdgcn_mfma_f32_16x16x32_bf16(a1, b3, acc[1][3], 0, 0, 0);
            acc[2][0] = __builtin_amdgcn_mfma_f32_16x16x32_bf16(a2, b0, acc[2][0], 0, 0, 0);
            acc[2][1] = __builtin_amdgcn_mfma_f32_16x16x32_bf16(a2, b1, acc[2][1], 0, 0, 0);
            acc[2][2] = __builtin_amdgcn_mfma_f32_16x16x32_bf16(a2, b2, acc[2][2], 0, 0, 0);
            acc[2][3] = __builtin_amdgcn_mfma_f32_16x16x32_bf16(a2, b3, acc[2][3], 0, 0, 0);
            acc[3][0] = __builtin_amdgcn_mfma_f32_16x16x32_bf16(a3, b0, acc[3][0], 0, 0, 0);
            acc[3][1] = __builtin_amdgcn_mfma_f32_16x16x32_bf16(a3, b1, acc[3][1], 0, 0, 0);
            acc[3][2] = __builtin_amdgcn_mfma_f32_16x16x32_bf16(a3, b2, acc[3][2], 0, 0, 0);
            acc[3][3] = __builtin_amdgcn_mfma_f32_16x16x32_bf16(a3, b3, acc[3][3], 0, 0, 0);
            __builtin_amdgcn_s_setprio(0);
            // k-half 1
            b0 = LDB8(0, 1); b1 = LDB8(1, 1); b2 = LDB8(2, 1); b3 = LDB8(3, 1);
            a0 = LDA8(0, 1); a1 = LDA8(1, 1); a2 = LDA8(2, 1); a3 = LDA8(3, 1);
            __builtin_amdgcn_s_setprio(1);
            acc[0][0] = __builtin_amdgcn_mfma_f32_16x16x32_bf16(a0, b0, acc[0][0], 0, 0, 0);
            acc[0][1] = __builtin_amdgcn_mfma_f32_16x16x32_bf16(a0, b1, acc[0][1], 0, 0, 0);
            acc[0][2] = __builtin_amdgcn_mfma_f32_16x16x32_bf16(a0, b2, acc[0][2], 0, 0, 0);
            acc[0][3] = __builtin_amdgcn_mfma_f32_16x16x32_bf16(a0, b3, acc[0][3], 0, 0, 0);
            acc[1][0] = __builtin_amdgcn_mfma_f32_16x16x32_bf16(a1, b0, acc[1][0], 0, 0, 0);
            acc[1][1] = __builtin_amdgcn_mfma_f32_16x16x32_bf16(a1, b1, acc[1][1], 0, 0, 0);
            acc[1][2] = __builtin_amdgcn_mfma_f32_16x16x32_bf16(a1, b2, acc[1][2], 0, 0, 0);
            acc[1][3] = __builtin_amdgcn_mfma_f32_16x16x32_bf16(a1, b3, acc[1][3], 0, 0, 0);
            acc[2][0] = __builtin_amdgcn_mfma_f32_16x16x32_bf16(a2, b0, acc[2][0], 0, 0, 0);
            acc[2][1] = __builtin_amdgcn_mfma_f32_16x16x32_bf16(a2, b1, acc[2][1], 0, 0, 0);
            acc[2][2] = __builtin_amdgcn_mfma_f32_16x16x32_bf16(a2, b2, acc[2][2], 0, 0, 0);
            acc[2][3] = __builtin_amdgcn_mfma_f32_16x16x32_bf16(a2, b3, acc[2][3], 0, 0, 0);
            acc[3][0] = __builtin_amdgcn_mfma_f32_16x16x32_bf16(a3, b0, acc[3][0], 0, 0, 0);
            acc[3][1] = __builtin_amdgcn_mfma_f32_16x16x32_bf16(a3, b1, acc[3][1], 0, 0, 0);
            acc[3][2] = __builtin_amdgcn_mfma_f32_16x16x32_bf16(a3, b2, acc[3][2], 0, 0, 0);
            acc[3][3] = __builtin_amdgcn_mfma_f32_16x16x32_bf16(a3, b3, acc[3][3], 0, 0, 0);
            __builtin_amdgcn_s_setprio(0);
        }
        cur = (cur == 2) ? 0 : cur + 1;
        sb  = (sb == 2) ? 0 : sb + 1;
    }
#undef LDA8
#undef LDB8

#pragma unroll
    for (int mt = 0; mt < 4; ++mt) {
#pragma unroll
        for (int nt = 0; nt < 4; ++nt) {
            const int gcol = bn0 + wn * 64 + nt * 16 + fr;
#pragma unroll
            for (int r = 0; r < 4; ++r) {
                const int grow = bm0 + wm * 64 + mt * 16 + fq * 4 + r;
                if (grow < M) {
                    float v = acc[mt][nt][r];
                    if (OMODE != 0 && OMODE != 8) v += bias[gcol];
                    if (OMODE == 0 || OMODE == 1) {
                        ((BF16*)Cout)[(size_t)grow * N + gcol] = f2bf(v);
                    } else if (OMODE == 4) {
                        int b = grow / 3136;
                        size_t xrow = (size_t)b * 3137 + 1 + (grow - b * 3136);
                        ((float*)Cout)[xrow * 768 + gcol] =
                            v + ((const float*)res)[xrow * 768 + gcol];
                    } else if (OMODE == 6) {
                        float u = v * (0.7978845608f + 0.0356774081f * v * v);
                        v = v / (1.0f + __expf(-2.0f * u));
                        ((BF16*)Cout)[(size_t)grow * N + gcol] = f2bf(v);
                    } else {  // 7, 8
                        v += ((const float*)res)[(size_t)grow * N + gcol];
                        ((float*)Cout)[(size_t)grow * N + gcol] = v;
                    }
                }
            }
        }
    }
}

// ---------------------------------------------------------------------------
// Temporal attention, one block per (group, head). L in {4,8,16}, d=64.
// ---------------------------------------------------------------------------
template <int L, int NT>
__global__ __launch_bounds__(NT) void temporal_attn(const BF16* __restrict__ qkv,
                                                    BF16* __restrict__ outp) {
    __shared__ float q[L * 64];
    __shared__ float k[L * 65];
    __shared__ float v[L * 64];
    __shared__ float S[L * L];
    const int bh = blockIdx.x;
    const int b = bh / 12, h = bh % 12;
    const int tid = threadIdx.x;
    const size_t rb = (size_t)b * L;
    for (int idx = tid; idx < L * 64; idx += NT) {
        int i = idx >> 6, d = idx & 63;
        size_t base = (rb + i) * 2304 + h * 64 + d;
        q[i * 64 + d] = bf2f(qkv[base]);
        k[i * 65 + d] = bf2f(qkv[base + 768]);
        v[i * 64 + d] = bf2f(qkv[base + 1536]);
    }
    __syncthreads();
    for (int idx = tid; idx < L * L; idx += NT) {
        int i = idx / L, j = idx % L;
        float a = 0.f;
#pragma unroll
        for (int d = 0; d < 64; ++d) a += q[i * 64 + d] * k[j * 65 + d];
        S[idx] = a * 0.125f;
    }
    __syncthreads();
    if (tid < L) {
        float mx = -1e30f;
        for (int j = 0; j < L; ++j) mx = fmaxf(mx, S[tid * L + j]);
        float sm = 0.f;
        for (int j = 0; j < L; ++j) { float e = __expf(S[tid * L + j] - mx); S[tid * L + j] = e; sm += e; }
        float inv = 1.0f / sm;
        for (int j = 0; j < L; ++j) S[tid * L + j] *= inv;
    }
    __syncthreads();
    for (int idx = tid; idx < L * 64; idx += NT) {
        int i = idx >> 6, d = idx & 63;
        float acc = 0.f;
#pragma unroll
        for (int j = 0; j < L; ++j) acc += S[i * L + j] * v[j * 64 + d];
        outp[(rb + i) * 768 + h * 64 + d] = f2bf(acc);
    }
}

// ---------------------------------------------------------------------------
// MFMA spatial attention. Block = (bt, h, qtile-of-64); 4 waves x 16 queries.
// ---------------------------------------------------------------------------
__global__ __launch_bounds__(256) void spatial_attn_mfma(const BF16* __restrict__ qkv,
                                                         BF16* __restrict__ outp) {
    const int bid = blockIdx.x;
    const int qt = bid & 3;
    const int h = (bid >> 2) % 12;
    const int bt = bid / 48;
    const int rowbase = bt * 197;
    __shared__ BF16 Ks[208 * 72];
    __shared__ BF16 Vt[64 * 232];
    __shared__ BF16 Pl[4][16 * 232];
    const int tid = threadIdx.x;
    const int lane = tid & 63;
    const int w = tid >> 6;
    const int ln = lane & 15;
    const int quad = lane >> 4;

    for (int it = tid; it < 208 * 8; it += 256) {
        int key = it >> 3, c = it & 7;
        int kc = key < 197 ? key : 196;
        short8 gk = *(const short8*)(qkv + (size_t)(rowbase + kc) * 2304 + 768 + h * 64 + c * 8);
        *(short8*)&Ks[key * 72 + c * 8] = gk;
    }
    for (int it = tid; it < 112 * 8; it += 256) {
        int p = it >> 3, c = it & 7;
        int kc0 = (2 * p < 197) ? 2 * p : 196;
        int kc1 = (2 * p + 1 < 197) ? 2 * p + 1 : 196;
        short8 a = *(const short8*)(qkv + (size_t)(rowbase + kc0) * 2304 + 1536 + h * 64 + c * 8);
        short8 b = *(const short8*)(qkv + (size_t)(rowbase + kc1) * 2304 + 1536 + h * 64 + c * 8);
#pragma unroll
        for (int e = 0; e < 8; ++e) {
            short2v pr;
            pr[0] = a[e];
            pr[1] = b[e];
            *(short2v*)&Vt[(c * 8 + e) * 232 + 2 * p] = pr;
        }
    }
    __syncthreads();

    const int m0 = qt * 64 + w * 16;
    int qrow = m0 + ln; if (qrow > 196) qrow = 196;
    const BF16* qptr = qkv + (size_t)(rowbase + qrow) * 2304 + h * 64 + quad * 8;
    short8 aq0 = *(const short8*)(qptr);
    short8 aq1 = *(const short8*)(qptr + 32);

    floatx4 sacc[13];
#pragma unroll
    for (int nt = 0; nt < 13; ++nt) sacc[nt] = (floatx4){0.f, 0.f, 0.f, 0.f};
#pragma unroll
    for (int nt = 0; nt < 13; ++nt) {
        const BF16* kb = &Ks[(nt * 16 + ln) * 72 + quad * 8];
        short8 b0 = *(const short8*)kb;
        short8 b1 = *(const short8*)(kb + 32);
        sacc[nt] = __builtin_amdgcn_mfma_f32_16x16x32_bf16(aq0, b0, sacc[nt], 0, 0, 0);
        sacc[nt] = __builtin_amdgcn_mfma_f32_16x16x32_bf16(aq1, b1, sacc[nt], 0, 0, 0);
    }

#pragma unroll
    for (int r = 0; r < 4; ++r) {
        float mx = -1e30f;
#pragma unroll
        for (int nt = 0; nt < 13; ++nt) {
            float s = sacc[nt][r] * 0.125f;
            sacc[nt][r] = s;
            if (nt * 16 + ln < 197) mx = fmaxf(mx, s);
        }
        mx = fmaxf(mx, __shfl_xor(mx, 1));
        mx = fmaxf(mx, __shfl_xor(mx, 2));
        mx = fmaxf(mx, __shfl_xor(mx, 4));
        mx = fmaxf(mx, __shfl_xor(mx, 8));
        float sum = 0.f;
#pragma unroll
        for (int nt = 0; nt < 13; ++nt) {
            float e = (nt * 16 + ln < 197) ? __expf(sacc[nt][r] - mx) : 0.f;
            sacc[nt][r] = e;
            sum += e;
        }
        sum += __shfl_xor(sum, 1);
        sum += __shfl_xor(sum, 2);
        sum += __shfl_xor(sum, 4);
        sum += __shfl_xor(sum, 8);
        float inv = 1.0f / sum;
#pragma unroll
        for (int nt = 0; nt < 13; ++nt) sacc[nt][r] *= inv;
    }

    BF16* pw = Pl[w];
#pragma unroll
    for (int nt = 0; nt < 13; ++nt)
#pragma unroll
        for (int r = 0; r < 4; ++r)
            pw[(quad * 4 + r) * 232 + nt * 16 + ln] = f2bf(sacc[nt][r]);
#pragma unroll
    for (int r = 0; r < 4; ++r)
        pw[(quad * 4 + r) * 232 + 208 + ln] = f2bf(0.f);

    floatx4 oacc[4];
#pragma unroll
    for (int nt = 0; nt < 4; ++nt) oacc[nt] = (floatx4){0.f, 0.f, 0.f, 0.f};
    for (int kb = 0; kb < 7; ++kb) {
        short8 ap = *(const short8*)&pw[ln * 232 + kb * 32 + quad * 8];
#pragma unroll
        for (int nt = 0; nt < 4; ++nt) {
            short8 bv = *(const short8*)&Vt[(nt * 16 + ln) * 232 + kb * 32 + quad * 8];
            oacc[nt] = __builtin_amdgcn_mfma_f32_16x16x32_bf16(ap, bv, oacc[nt], 0, 0, 0);
        }
    }

#pragma unroll
    for (int nt = 0; nt < 4; ++nt) {
        int dim = nt * 16 + ln;
#pragma unroll
        for (int r = 0; r < 4; ++r) {
            int q = m0 + quad * 4 + r;
            if (q < 197)
                outp[(size_t)(rowbase + q) * 768 + h * 64 + dim] = f2bf(oacc[nt][r]);
        }
    }
}

// ---------------------------------------------------------------------------
// cls second attention (tiny)
// ---------------------------------------------------------------------------
__global__ __launch_bounds__(256) void cls_attn_kernel(const float* __restrict__ clsln,
                                                       float* __restrict__ clsout) {
    const int b = blockIdx.x;
    const int tid = threadIdx.x;
    __shared__ float dots[16];
    __shared__ float aw[16];
    const int t = tid >> 4, l16 = tid & 15;
    const float* tgt = clsln + (size_t)(b * 16 + 15) * 768;
    const float* row = clsln + (size_t)(b * 16 + t) * 768;
    float p = 0.f;
    for (int c = l16; c < 768; c += 16) p += tgt[c] * row[c];
#pragma unroll
    for (int o = 8; o > 0; o >>= 1) p += __shfl_down(p, o, 16);
    if (l16 == 0) dots[t] = p;
    __syncthreads();
    if (tid == 0) {
        float mx = -1e30f;
        for (int j = 0; j < 16; ++j) mx = fmaxf(mx, dots[j]);
        float s = 0.f;
        for (int j = 0; j < 16; ++j) { aw[j] = __expf(dots[j] - mx); s += aw[j]; }
        float inv = 1.0f / s;
        for (int j = 0; j < 16; ++j) aw[j] *= inv;
    }
    __syncthreads();
    for (int c = tid; c < 768; c += 256) {
        float acc = 0.f;
#pragma unroll
        for (int j = 0; j < 16; ++j) acc += aw[j] * clsln[(size_t)(b * 16 + j) * 768 + c];
        clsout[(size_t)b * 768 + c] = acc;
    }
}

// In-place x_cat build in d_out.
__global__ __launch_bounds__(256) void xcat_kernel(const float* __restrict__ x,
                                                   const BF16* __restrict__ res_sp,
                                                   const float* __restrict__ clsout,
                                                   float* outbuf) {
    const int gidx = blockIdx.x;
    const int b = gidx / 3137, j = gidx - b * 3137;
    const int tid = threadIdx.x;
    if (j == 0) {
        const float* xr = x + (size_t)b * 3137 * 768;
        const float* cr = clsout + (size_t)b * 768;
#pragma unroll
        for (int i = 0; i < 3; ++i) {
            int c = tid + i * 256;
            outbuf[(size_t)gidx * 768 + c] = xr[c] + cr[c];
        }
    } else {
        const int p = j - 1, k = p >> 4, t = p & 15;
        const BF16* rs = res_sp + (size_t)((b * 16 + t) * 197 + 1 + k) * 768;
#pragma unroll
        for (int i = 0; i < 3; ++i) {
            int c = tid + i * 256;
            outbuf[(size_t)gidx * 768 + c] = outbuf[(size_t)gidx * 768 + c] + bf2f(rs[c]);
        }
    }
}

// ---------------------------------------------------------------------------
extern "C" void kernel_launch(void* const* d_in, const int* in_sizes, int n_in,
                              void* d_out, int out_size, void* d_ws, size_t ws_size,
                              hipStream_t stream) {
    const float* x       = (const float*)d_in[0];
    const float* ln1_g   = (const float*)d_in[4];
    const float* ln1_b   = (const float*)d_in[5];
    const float* lnt_g   = (const float*)d_in[6];
    const float* lnt_b   = (const float*)d_in[7];
    const float* ln2_g   = (const float*)d_in[8];
    const float* ln2_b   = (const float*)d_in[9];
    const float* lncls_g = (const float*)d_in[10];
    const float* lncls_b = (const float*)d_in[11];
    const float* Wqkv_s  = (const float*)d_in[12];
    const float* Wproj_s = (const float*)d_in[13];
    const float* bproj_s = (const float*)d_in[14];
    const float* Wqkv4   = (const float*)d_in[15];
    const float* Wqkv8   = (const float*)d_in[16];
    const float* Wqkv16  = (const float*)d_in[17];
    const float* Wp4     = (const float*)d_in[18];
    const float* bp4     = (const float*)d_in[19];
    const float* Wp8     = (const float*)d_in[20];
    const float* bp8     = (const float*)d_in[21];
    const float* Wp16    = (const float*)d_in[22];
    const float* bp16    = (const float*)d_in[23];
    const float* Wtfc    = (const float*)d_in[24];
    const float* btfc    = (const float*)d_in[25];
    const float* Wfc1    = (const float*)d_in[26];
    const float* bfc1    = (const float*)d_in[27];
    const float* Wfc2    = (const float*)d_in[28];
    const float* bfc2    = (const float*)d_in[29];
    float* out = (float*)d_out;

    // ---- workspace layout (bytes), lifetime-aliased; peak = 96,694,272 (known-good)
    const size_t oW0 = 0;
    const size_t oW1 = 4718592;
    const size_t oR1 = 9437184;
    const size_t oR2 = 28803072;
    const size_t oR3 = 48070656;
    const size_t oR4 = 77119488;
    const size_t oCL = 96485376;
    const size_t oCO = 96681984;
    const size_t NEED = 96694272;
    if (ws_size < NEED) return;
    char* ws = (char*)d_ws;

    BF16* w0       = (BF16*)(ws + oW0);
    BF16* w1       = (BF16*)(ws + oW1);
    BF16* xtn      = (BF16*)(ws + oR1);
    BF16* atts     = (BF16*)(ws + oR1);
    BF16* hln      = (BF16*)(ws + oR1);
    BF16* res_temp = (BF16*)(ws + oR2);
    BF16* h1       = (BF16*)(ws + oR2);
    BF16* qkv      = (BF16*)(ws + oR3);
    BF16* att      = (BF16*)(ws + oR4);
    BF16* xsn      = (BF16*)(ws + oR4);
    BF16* res_sp   = (BF16*)(ws + oR4);
    float* clsln   = (float*)(ws + oCL);
    float* clsout  = (float*)(ws + oCO);

    // ---- temporal LN
    ln_kernel<0><<<12544, 256, 0, stream>>>(x, nullptr, nullptr, lnt_g, lnt_b, xtn, nullptr);

    // ---- scale 16 (2 row-chunks of 6272)
    wtrans<<<dim3(24, 72), 256, 0, stream>>>(Wqkv16, w0, 768, 2304);
    for (int c = 0; c < 2; ++c) {
        gemm_ring<0, 0><<<dim3(18, 25), 512, 0, stream>>>(xtn + (size_t)c * 6272 * 768, w0, nullptr, nullptr, qkv, 6272, 2304, 768);
        temporal_attn<16, 256><<<4704, 256, 0, stream>>>(qkv, att + (size_t)c * 6272 * 768);
    }
    wtrans<<<dim3(24, 24), 256, 0, stream>>>(Wp16, w1, 768, 768);
    gemm_ring<0, 1><<<dim3(6, 49), 512, 0, stream>>>(att, w1, bp16, nullptr, res_temp, 12544, 768, 768);

    // ---- scale 8
    wtrans<<<dim3(24, 72), 256, 0, stream>>>(Wqkv8, w0, 768, 2304);
    gemm_ring<1, 0><<<dim3(18, 25), 512, 0, stream>>>(xtn, w0, nullptr, nullptr, qkv, 6272, 2304, 768);
    temporal_attn<8, 64><<<9408, 64, 0, stream>>>(qkv, att);
    wtrans<<<dim3(24, 24), 256, 0, stream>>>(Wp8, w1, 768, 768);
    gemm_bf16<0, 2><<<dim3(6, 49), 256, 0, stream>>>(att, w1, bp8, nullptr, res_temp, 6272, 768, 768);

    // ---- scale 4
    wtrans<<<dim3(24, 72), 256, 0, stream>>>(Wqkv4, w0, 768, 2304);
    gemm_ring<2, 0><<<dim3(18, 13), 512, 0, stream>>>(xtn, w0, nullptr, nullptr, qkv, 3136, 2304, 768);
    temporal_attn<4, 64><<<9408, 64, 0, stream>>>(qkv, att);
    wtrans<<<dim3(24, 24), 256, 0, stream>>>(Wp4, w1, 768, 768);
    gemm_bf16<0, 3><<<dim3(6, 25), 256, 0, stream>>>(att, w1, bp4, nullptr, res_temp, 3136, 768, 768);

    // ---- temporal FC + x residual -> xtfull stored in d_out at x-like rows
    wtrans<<<dim3(24, 24), 256, 0, stream>>>(Wtfc, w0, 768, 768);
    gemm_ring<0, 4><<<dim3(6, 49), 512, 0, stream>>>(res_temp, w0, btfc, x, out, 12544, 768, 768);

    // ---- spatial path (2 chunks of 32 bt-groups = 6304 rows)
    ln_kernel<1><<<12608, 256, 0, stream>>>(x, out, nullptr, ln1_g, ln1_b, xsn, nullptr);
    wtrans<<<dim3(24, 72), 256, 0, stream>>>(Wqkv_s, w1, 768, 2304);
    for (int c = 0; c < 2; ++c) {
        gemm_ring<0, 0><<<dim3(18, 25), 512, 0, stream>>>(xsn + (size_t)c * 6304 * 768, w1, nullptr, nullptr, qkv, 6304, 2304, 768);
        spatial_attn_mfma<<<1536, 256, 0, stream>>>(qkv, atts + (size_t)c * 6304 * 768);
    }
    wtrans<<<dim3(24, 24), 256, 0, stream>>>(Wproj_s, w0, 768, 768);
    gemm_ring<0, 1><<<dim3(6, 50), 512, 0, stream>>>(atts, w0, bproj_s, nullptr, res_sp, 12608, 768, 768);

    // ---- cls path
    ln_kernel<3><<<64, 256, 0, stream>>>(nullptr, nullptr, res_sp, lncls_g, lncls_b, nullptr, clsln);
    cls_attn_kernel<<<4, 256, 0, stream>>>(clsln, clsout);

    // ---- combine (in-place in d_out)
    xcat_kernel<<<12548, 256, 0, stream>>>(x, res_sp, clsout, out);
    ln_kernel<2><<<12548, 256, 0, stream>>>(out, nullptr, nullptr, ln2_g, ln2_b, hln, nullptr);

    // ---- MLP: full-M, hidden split in 2 halves; fc2 accumulates into d_out
    wtrans<<<dim3(24, 96), 256, 0, stream>>>(Wfc1, w0, 768, 3072);
    wtrans<<<dim3(48, 24), 256, 0, stream>>>(Wfc2, w1, 1536, 768);
    wtrans<<<dim3(48, 24), 256, 0, stream>>>(Wfc2 + (size_t)1536 * 768, w1 + (size_t)768 * 1536, 1536, 768);

    // half a
    gemm_ring<0, 6><<<dim3(12, 50), 512, 0, stream>>>(hln, w0, bfc1, nullptr, h1, 12548, 1536, 768);
    gemm_ring<0, 7><<<dim3(6, 50), 512, 0, stream>>>(h1, w1, bfc2, out, out, 12548, 768, 1536);
    // half b
    gemm_ring<0, 6><<<dim3(12, 50), 512, 0, stream>>>(hln, w0 + (size_t)1536 * 768, bfc1 + 1536, nullptr, h1, 12548, 1536, 768);
    gemm_ring<0, 8><<<dim3(6, 50), 512, 0, stream>>>(h1, w1 + (size_t)768 * 1536, nullptr, out, out, 12548, 768, 1536);
}

// Round 5
// 1047.679 us; speedup vs baseline: 1.1955x; 1.1955x over previous
//
#include <hip/hip_runtime.h>
#include <hip/hip_bf16.h>
#include <stdint.h>

#define BF16 __hip_bfloat16

typedef __attribute__((ext_vector_type(8))) short short8;
typedef __attribute__((ext_vector_type(2))) short short2v;
typedef __attribute__((ext_vector_type(4))) float floatx4;

typedef const __attribute__((address_space(1))) void* gas_cvp;
typedef __attribute__((address_space(3))) void* las_vp;

__device__ __forceinline__ float bf2f(BF16 v) { return __bfloat162float(v); }
__device__ __forceinline__ BF16 f2bf(float v) { return __float2bfloat16(v); }

// ---------------------------------------------------------------------------
// Weight fp32 [K,N] -> bf16 transposed [N,K]
// ---------------------------------------------------------------------------
__global__ __launch_bounds__(256) void wtrans(const float* __restrict__ W,
                                              BF16* __restrict__ Wt, int K, int N) {
    __shared__ float t[32][33];
    int k0 = blockIdx.x * 32, n0 = blockIdx.y * 32;
    int tx = threadIdx.x & 31, ty = threadIdx.x >> 5;  // ty 0..7
#pragma unroll
    for (int i = 0; i < 32; i += 8) t[ty + i][tx] = W[(size_t)(k0 + ty + i) * N + n0 + tx];
    __syncthreads();
#pragma unroll
    for (int i = 0; i < 32; i += 8)
        Wt[(size_t)(n0 + ty + i) * K + k0 + tx] = f2bf(t[tx][ty + i]);
}

// ---------------------------------------------------------------------------
// LayerNorm over 768 cols, block=256.
// MODE 0: rows of x[:,1:,:]  -> bf16
// MODE 1: spatial xs rows (cls from x fp32 / patch from xtfull-in-dout) -> bf16
// MODE 2: plain fp32 rows -> bf16
// MODE 3: cls rows (row*197) of bf16 src -> fp32
// ---------------------------------------------------------------------------
template <int MODE>
__global__ __launch_bounds__(256) void ln_kernel(const float* __restrict__ src0,
                                                 const float* __restrict__ src1,
                                                 const BF16* __restrict__ srcb,
                                                 const float* __restrict__ g,
                                                 const float* __restrict__ bta,
                                                 BF16* __restrict__ dst_bf,
                                                 float* __restrict__ dst_f) {
    const int r = blockIdx.x, tid = threadIdx.x;
    float x0, x1, x2;
    if (MODE == 3) {
        const BF16* src = srcb + (size_t)r * 197 * 768;
        x0 = bf2f(src[tid]); x1 = bf2f(src[tid + 256]); x2 = bf2f(src[tid + 512]);
    } else {
        const float* src;
        if (MODE == 0) {
            int b = r / 3136, rr = r - b * 3136;
            src = src0 + ((size_t)b * 3137 + 1 + rr) * 768;
        } else if (MODE == 1) {
            int bt = r / 197, j = r - bt * 197;
            int b = bt >> 4, t = bt & 15;
            if (j == 0) src = src0 + (size_t)b * 3137 * 768;
            else        src = src1 + ((size_t)(b * 3137 + 1) + (size_t)(j - 1) * 16 + t) * 768;
        } else {
            src = src0 + (size_t)r * 768;
        }
        x0 = src[tid]; x1 = src[tid + 256]; x2 = src[tid + 512];
    }
    float s = x0 + x1 + x2;
    float ss = x0 * x0 + x1 * x1 + x2 * x2;
    __shared__ float red[8];
#pragma unroll
    for (int o = 32; o > 0; o >>= 1) { s += __shfl_down(s, o); ss += __shfl_down(ss, o); }
    if ((tid & 63) == 0) { red[tid >> 6] = s; red[4 + (tid >> 6)] = ss; }
    __syncthreads();
    s = red[0] + red[1] + red[2] + red[3];
    ss = red[4] + red[5] + red[6] + red[7];
    const float mu = s * (1.0f / 768.0f);
    const float var = ss * (1.0f / 768.0f) - mu * mu;
    const float rstd = rsqrtf(var + 1e-5f);
#pragma unroll
    for (int i = 0; i < 3; ++i) {
        int c = tid + i * 256;
        float xv = (i == 0) ? x0 : (i == 1) ? x1 : x2;
        float y = (xv - mu) * rstd * g[c] + bta[c];
        if (MODE == 3) dst_f[(size_t)r * 768 + c] = y;
        else           dst_bf[(size_t)r * 768 + c] = f2bf(y);
    }
}

// ---------------------------------------------------------------------------
// bf16 GEMM: C[M,N] = A'[M,K] @ Bt[N,K]^T with row-mapped A and fused epilogue.
// BK=64, XOR-swizzled LDS k-blocks (phys = logical ^ (row&7)), grid x=N-tiles.
// XCD-chunked bijective block swizzle (R1-verified: FETCH 80->29MB, fc1 94->67us).
// AMAP: 0 identity; 1 scale8; 2 scale4
// OMODE: 0 bf16 plain; 1 bf16 +bias; 2 merge8 RMW; 3 merge4 RMW;
//        4 fp32 +bias +x-residual at CLS-skip row; 6 bf16 +bias+gelu;
//        7 fp32 +bias+res(in-place ok); 8 fp32 +res accumulate
// ---------------------------------------------------------------------------
template <int AMAP, int OMODE>
__global__ __launch_bounds__(256) void gemm_bf16(const BF16* __restrict__ A,
                                                 const BF16* __restrict__ Bt,
                                                 const float* __restrict__ bias,
                                                 const void* res,
                                                 void* Cout,
                                                 int M, int N, int K) {
    __shared__ BF16 Al[128 * 64];
    __shared__ BF16 Bl[128 * 64];
    const int tid = threadIdx.x;
    const int lane = tid & 63;
    const int w = tid >> 6;

    const int gx = gridDim.x;
    const int nwg = gx * (int)gridDim.y;
    const int orig = (int)blockIdx.y * gx + (int)blockIdx.x;
    const int xcd = orig & 7;
    const int idx = orig >> 3;
    const int q8 = nwg >> 3, r8 = nwg & 7;
    const int wgid = (xcd < r8 ? xcd * (q8 + 1) : r8 * (q8 + 1) + (xcd - r8) * q8) + idx;
    const int bn0 = (wgid % gx) * 128;  // N-tile fast-varying: chunk-mates share A
    const int bm0 = (wgid / gx) * 128;

    // staging: 32 chunks (16 A + 16 B) of 8 rows x 128 B; wave w owns 8 chunks.
    // lane -> (row-in-chunk, phys k-block); fetch logical block phys^row for swizzle.
    const BF16* gsrc[8];
    BF16* ldst[8];
    const int rin = lane >> 3;
    const int kblk = (lane & 7) ^ rin;
#pragma unroll
    for (int j = 0; j < 8; ++j) {
        int c = w * 8 + j;
        if (c < 16) {
            int gr = bm0 + c * 8 + rin;
            if (gr > M - 1) gr = M - 1;
            if (AMAP == 1) gr = (gr >> 3) * 16 + 8 + (gr & 7);
            if (AMAP == 2) gr = (gr >> 2) * 16 + 12 + (gr & 3);
            gsrc[j] = A + (size_t)gr * K + kblk * 8;
            ldst[j] = Al + c * 512;
        } else {
            int gn = bn0 + (c - 16) * 8 + rin;
            gsrc[j] = Bt + (size_t)gn * K + kblk * 8;
            ldst[j] = Bl + (c - 16) * 512;
        }
    }

    const int wm = (w & 1) * 64;
    const int wn = (w >> 1) * 64;
    const int fr = lane & 15;
    const int fq = lane >> 4;
    const int sw = fr & 7;
    const int o0 = (fq ^ sw) * 8;        // k-half 0: logical block fq
    const int o1 = ((fq + 4) ^ sw) * 8;  // k-half 1: logical block fq+4
    const BF16* pa[4];
    const BF16* pb[4];
#pragma unroll
    for (int t = 0; t < 4; ++t) {
        pa[t] = Al + (wm + t * 16 + fr) * 64;
        pb[t] = Bl + (wn + t * 16 + fr) * 64;
    }

    floatx4 acc[4][4];
#pragma unroll
    for (int i = 0; i < 4; ++i)
#pragma unroll
        for (int j = 0; j < 4; ++j) acc[i][j] = (floatx4){0.f, 0.f, 0.f, 0.f};

    for (int k0 = 0; k0 < K; k0 += 64) {
#pragma unroll
        for (int j = 0; j < 8; ++j) {
            __builtin_amdgcn_global_load_lds((gas_cvp)gsrc[j], (las_vp)ldst[j], 16, 0, 0);
            gsrc[j] += 64;
        }
        __syncthreads();
        {
            short8 af[4], bfr[4];
#pragma unroll
            for (int t = 0; t < 4; ++t) {
                af[t] = *(const short8*)(pa[t] + o0);
                bfr[t] = *(const short8*)(pb[t] + o0);
            }
#pragma unroll
            for (int mt = 0; mt < 4; ++mt)
#pragma unroll
                for (int nt = 0; nt < 4; ++nt)
                    acc[mt][nt] = __builtin_amdgcn_mfma_f32_16x16x32_bf16(af[mt], bfr[nt], acc[mt][nt], 0, 0, 0);
#pragma unroll
            for (int t = 0; t < 4; ++t) {
                af[t] = *(const short8*)(pa[t] + o1);
                bfr[t] = *(const short8*)(pb[t] + o1);
            }
#pragma unroll
            for (int mt = 0; mt < 4; ++mt)
#pragma unroll
                for (int nt = 0; nt < 4; ++nt)
                    acc[mt][nt] = __builtin_amdgcn_mfma_f32_16x16x32_bf16(af[mt], bfr[nt], acc[mt][nt], 0, 0, 0);
        }
        __syncthreads();
    }

#pragma unroll
    for (int mt = 0; mt < 4; ++mt) {
#pragma unroll
        for (int nt = 0; nt < 4; ++nt) {
            const int gcol = bn0 + wn + nt * 16 + fr;
#pragma unroll
            for (int r = 0; r < 4; ++r) {
                const int grow = bm0 + wm + mt * 16 + fq * 4 + r;
                if (grow < M) {
                    float v = acc[mt][nt][r];
                    if (OMODE != 0 && OMODE != 8) v += bias[gcol];
                    if (OMODE == 0 || OMODE == 1) {
                        ((BF16*)Cout)[(size_t)grow * N + gcol] = f2bf(v);
                    } else if (OMODE == 2) {
                        int t8 = grow & 7;
                        int rr = (grow >> 3) * 16 + 8 + t8;
                        float w8 = (t8 < 4) ? 0.5f : 0.25f;
                        BF16* R = (BF16*)Cout;
                        size_t o = (size_t)rr * 768 + gcol;
                        R[o] = f2bf(0.5f * bf2f(R[o]) + w8 * v);
                    } else if (OMODE == 3) {
                        int t4 = grow & 3;
                        int rr = (grow >> 2) * 16 + 12 + t4;
                        BF16* R = (BF16*)Cout;
                        size_t o = (size_t)rr * 768 + gcol;
                        R[o] = f2bf(bf2f(R[o]) + 0.25f * v);
                    } else if (OMODE == 4) {
                        int b = grow / 3136;
                        size_t xrow = (size_t)b * 3137 + 1 + (grow - b * 3136);
                        ((float*)Cout)[xrow * 768 + gcol] =
                            v + ((const float*)res)[xrow * 768 + gcol];
                    } else if (OMODE == 6) {
                        // fast GELU: x*sigmoid(2*0.7978845608*(x+0.044715x^3))
                        float u = v * (0.7978845608f + 0.0356774081f * v * v);
                        v = v / (1.0f + __expf(-2.0f * u));
                        ((BF16*)Cout)[(size_t)grow * N + gcol] = f2bf(v);
                    } else {  // 7, 8
                        v += ((const float*)res)[(size_t)grow * N + gcol];
                        ((float*)Cout)[(size_t)grow * N + gcol] = v;
                    }
                }
            }
        }
    }
}

// ---------------------------------------------------------------------------
// Temporal attention, one block per (group, head). L in {4,8,16}, d=64.
// ---------------------------------------------------------------------------
template <int L, int NT>
__global__ __launch_bounds__(NT) void temporal_attn(const BF16* __restrict__ qkv,
                                                    BF16* __restrict__ outp) {
    __shared__ float q[L * 64];
    __shared__ float k[L * 65];
    __shared__ float v[L * 64];
    __shared__ float S[L * L];
    const int bh = blockIdx.x;
    const int b = bh / 12, h = bh % 12;
    const int tid = threadIdx.x;
    const size_t rb = (size_t)b * L;
    for (int idx = tid; idx < L * 64; idx += NT) {
        int i = idx >> 6, d = idx & 63;
        size_t base = (rb + i) * 2304 + h * 64 + d;
        q[i * 64 + d] = bf2f(qkv[base]);
        k[i * 65 + d] = bf2f(qkv[base + 768]);
        v[i * 64 + d] = bf2f(qkv[base + 1536]);
    }
    __syncthreads();
    for (int idx = tid; idx < L * L; idx += NT) {
        int i = idx / L, j = idx % L;
        float a = 0.f;
#pragma unroll
        for (int d = 0; d < 64; ++d) a += q[i * 64 + d] * k[j * 65 + d];
        S[idx] = a * 0.125f;
    }
    __syncthreads();
    if (tid < L) {
        float mx = -1e30f;
        for (int j = 0; j < L; ++j) mx = fmaxf(mx, S[tid * L + j]);
        float sm = 0.f;
        for (int j = 0; j < L; ++j) { float e = __expf(S[tid * L + j] - mx); S[tid * L + j] = e; sm += e; }
        float inv = 1.0f / sm;
        for (int j = 0; j < L; ++j) S[tid * L + j] *= inv;
    }
    __syncthreads();
    for (int idx = tid; idx < L * 64; idx += NT) {
        int i = idx >> 6, d = idx & 63;
        float acc = 0.f;
#pragma unroll
        for (int j = 0; j < L; ++j) acc += S[i * L + j] * v[j * 64 + d];
        outp[(rb + i) * 768 + h * 64 + d] = f2bf(acc);
    }
}

// ---------------------------------------------------------------------------
// MFMA spatial attention. Block = (bt, h, qtile-of-64); 4 waves x 16 queries.
// ---------------------------------------------------------------------------
__global__ __launch_bounds__(256) void spatial_attn_mfma(const BF16* __restrict__ qkv,
                                                         BF16* __restrict__ outp) {
    const int bid = blockIdx.x;
    const int qt = bid & 3;
    const int h = (bid >> 2) % 12;
    const int bt = bid / 48;
    const int rowbase = bt * 197;
    __shared__ BF16 Ks[208 * 72];
    __shared__ BF16 Vt[64 * 232];
    __shared__ BF16 Pl[4][16 * 232];
    const int tid = threadIdx.x;
    const int lane = tid & 63;
    const int w = tid >> 6;
    const int ln = lane & 15;
    const int quad = lane >> 4;

    for (int it = tid; it < 208 * 8; it += 256) {
        int key = it >> 3, c = it & 7;
        int kc = key < 197 ? key : 196;
        short8 gk = *(const short8*)(qkv + (size_t)(rowbase + kc) * 2304 + 768 + h * 64 + c * 8);
        *(short8*)&Ks[key * 72 + c * 8] = gk;
    }
    for (int it = tid; it < 112 * 8; it += 256) {
        int p = it >> 3, c = it & 7;
        int kc0 = (2 * p < 197) ? 2 * p : 196;
        int kc1 = (2 * p + 1 < 197) ? 2 * p + 1 : 196;
        short8 a = *(const short8*)(qkv + (size_t)(rowbase + kc0) * 2304 + 1536 + h * 64 + c * 8);
        short8 b = *(const short8*)(qkv + (size_t)(rowbase + kc1) * 2304 + 1536 + h * 64 + c * 8);
#pragma unroll
        for (int e = 0; e < 8; ++e) {
            short2v pr;
            pr[0] = a[e];
            pr[1] = b[e];
            *(short2v*)&Vt[(c * 8 + e) * 232 + 2 * p] = pr;
        }
    }
    __syncthreads();

    const int m0 = qt * 64 + w * 16;
    int qrow = m0 + ln; if (qrow > 196) qrow = 196;
    const BF16* qptr = qkv + (size_t)(rowbase + qrow) * 2304 + h * 64 + quad * 8;
    short8 aq0 = *(const short8*)(qptr);
    short8 aq1 = *(const short8*)(qptr + 32);

    floatx4 sacc[13];
#pragma unroll
    for (int nt = 0; nt < 13; ++nt) sacc[nt] = (floatx4){0.f, 0.f, 0.f, 0.f};
#pragma unroll
    for (int nt = 0; nt < 13; ++nt) {
        const BF16* kb = &Ks[(nt * 16 + ln) * 72 + quad * 8];
        short8 b0 = *(const short8*)kb;
        short8 b1 = *(const short8*)(kb + 32);
        sacc[nt] = __builtin_amdgcn_mfma_f32_16x16x32_bf16(aq0, b0, sacc[nt], 0, 0, 0);
        sacc[nt] = __builtin_amdgcn_mfma_f32_16x16x32_bf16(aq1, b1, sacc[nt], 0, 0, 0);
    }

#pragma unroll
    for (int r = 0; r < 4; ++r) {
        float mx = -1e30f;
#pragma unroll
        for (int nt = 0; nt < 13; ++nt) {
            float s = sacc[nt][r] * 0.125f;
            sacc[nt][r] = s;
            if (nt * 16 + ln < 197) mx = fmaxf(mx, s);
        }
        mx = fmaxf(mx, __shfl_xor(mx, 1));
        mx = fmaxf(mx, __shfl_xor(mx, 2));
        mx = fmaxf(mx, __shfl_xor(mx, 4));
        mx = fmaxf(mx, __shfl_xor(mx, 8));
        float sum = 0.f;
#pragma unroll
        for (int nt = 0; nt < 13; ++nt) {
            float e = (nt * 16 + ln < 197) ? __expf(sacc[nt][r] - mx) : 0.f;
            sacc[nt][r] = e;
            sum += e;
        }
        sum += __shfl_xor(sum, 1);
        sum += __shfl_xor(sum, 2);
        sum += __shfl_xor(sum, 4);
        sum += __shfl_xor(sum, 8);
        float inv = 1.0f / sum;
#pragma unroll
        for (int nt = 0; nt < 13; ++nt) sacc[nt][r] *= inv;
    }

    BF16* pw = Pl[w];
#pragma unroll
    for (int nt = 0; nt < 13; ++nt)
#pragma unroll
        for (int r = 0; r < 4; ++r)
            pw[(quad * 4 + r) * 232 + nt * 16 + ln] = f2bf(sacc[nt][r]);
#pragma unroll
    for (int r = 0; r < 4; ++r)
        pw[(quad * 4 + r) * 232 + 208 + ln] = f2bf(0.f);

    floatx4 oacc[4];
#pragma unroll
    for (int nt = 0; nt < 4; ++nt) oacc[nt] = (floatx4){0.f, 0.f, 0.f, 0.f};
    for (int kb = 0; kb < 7; ++kb) {
        short8 ap = *(const short8*)&pw[ln * 232 + kb * 32 + quad * 8];
#pragma unroll
        for (int nt = 0; nt < 4; ++nt) {
            short8 bv = *(const short8*)&Vt[(nt * 16 + ln) * 232 + kb * 32 + quad * 8];
            oacc[nt] = __builtin_amdgcn_mfma_f32_16x16x32_bf16(ap, bv, oacc[nt], 0, 0, 0);
        }
    }

#pragma unroll
    for (int nt = 0; nt < 4; ++nt) {
        int dim = nt * 16 + ln;
#pragma unroll
        for (int r = 0; r < 4; ++r) {
            int q = m0 + quad * 4 + r;
            if (q < 197)
                outp[(size_t)(rowbase + q) * 768 + h * 64 + dim] = f2bf(oacc[nt][r]);
        }
    }
}

// ---------------------------------------------------------------------------
// cls second attention (tiny)
// ---------------------------------------------------------------------------
__global__ __launch_bounds__(256) void cls_attn_kernel(const float* __restrict__ clsln,
                                                       float* __restrict__ clsout) {
    const int b = blockIdx.x;
    const int tid = threadIdx.x;
    __shared__ float dots[16];
    __shared__ float aw[16];
    const int t = tid >> 4, l16 = tid & 15;
    const float* tgt = clsln + (size_t)(b * 16 + 15) * 768;
    const float* row = clsln + (size_t)(b * 16 + t) * 768;
    float p = 0.f;
    for (int c = l16; c < 768; c += 16) p += tgt[c] * row[c];
#pragma unroll
    for (int o = 8; o > 0; o >>= 1) p += __shfl_down(p, o, 16);
    if (l16 == 0) dots[t] = p;
    __syncthreads();
    if (tid == 0) {
        float mx = -1e30f;
        for (int j = 0; j < 16; ++j) mx = fmaxf(mx, dots[j]);
        float s = 0.f;
        for (int j = 0; j < 16; ++j) { aw[j] = __expf(dots[j] - mx); s += aw[j]; }
        float inv = 1.0f / s;
        for (int j = 0; j < 16; ++j) aw[j] *= inv;
    }
    __syncthreads();
    for (int c = tid; c < 768; c += 256) {
        float acc = 0.f;
#pragma unroll
        for (int j = 0; j < 16; ++j) acc += aw[j] * clsln[(size_t)(b * 16 + j) * 768 + c];
        clsout[(size_t)b * 768 + c] = acc;
    }
}

// ---------------------------------------------------------------------------
// Fused x_cat build + ln2: row j=0 gets x_cls + cls_sp; rows j>=1 get
// (already-present xtfull) + x_s.  Writes fp32 x_cat to outbuf AND the
// LayerNorm'd bf16 row to hln — saves the separate ln_kernel<2> pass
// (one full 38.5 MB fp32 re-read + 12548-block launch).
// ---------------------------------------------------------------------------
__global__ __launch_bounds__(256) void xcat_ln_kernel(const float* __restrict__ x,
                                                      const BF16* __restrict__ res_sp,
                                                      const float* __restrict__ clsout,
                                                      const float* __restrict__ g,
                                                      const float* __restrict__ bta,
                                                      float* outbuf,
                                                      BF16* __restrict__ hln) {
    const int gidx = blockIdx.x;
    const int b = gidx / 3137, j = gidx - b * 3137;
    const int tid = threadIdx.x;
    float v0, v1, v2;
    if (j == 0) {
        const float* xr = x + (size_t)b * 3137 * 768;
        const float* cr = clsout + (size_t)b * 768;
        v0 = xr[tid] + cr[tid];
        v1 = xr[tid + 256] + cr[tid + 256];
        v2 = xr[tid + 512] + cr[tid + 512];
    } else {
        const int p = j - 1, k = p >> 4, t = p & 15;
        const BF16* rs = res_sp + (size_t)((b * 16 + t) * 197 + 1 + k) * 768;
        float* orow = outbuf + (size_t)gidx * 768;
        v0 = orow[tid] + bf2f(rs[tid]);
        v1 = orow[tid + 256] + bf2f(rs[tid + 256]);
        v2 = orow[tid + 512] + bf2f(rs[tid + 512]);
    }
    float* orow = outbuf + (size_t)gidx * 768;
    orow[tid] = v0; orow[tid + 256] = v1; orow[tid + 512] = v2;

    // LayerNorm over the row (values already in registers)
    float s = v0 + v1 + v2;
    float ss = v0 * v0 + v1 * v1 + v2 * v2;
    __shared__ float red[8];
#pragma unroll
    for (int o = 32; o > 0; o >>= 1) { s += __shfl_down(s, o); ss += __shfl_down(ss, o); }
    if ((tid & 63) == 0) { red[tid >> 6] = s; red[4 + (tid >> 6)] = ss; }
    __syncthreads();
    s = red[0] + red[1] + red[2] + red[3];
    ss = red[4] + red[5] + red[6] + red[7];
    const float mu = s * (1.0f / 768.0f);
    const float var = ss * (1.0f / 768.0f) - mu * mu;
    const float rstd = rsqrtf(var + 1e-5f);
#pragma unroll
    for (int i = 0; i < 3; ++i) {
        int c = tid + i * 256;
        float xv = (i == 0) ? v0 : (i == 1) ? v1 : v2;
        hln[(size_t)gidx * 768 + c] = f2bf((xv - mu) * rstd * g[c] + bta[c]);
    }
}

// ---------------------------------------------------------------------------
extern "C" void kernel_launch(void* const* d_in, const int* in_sizes, int n_in,
                              void* d_out, int out_size, void* d_ws, size_t ws_size,
                              hipStream_t stream) {
    const float* x       = (const float*)d_in[0];
    const float* ln1_g   = (const float*)d_in[4];
    const float* ln1_b   = (const float*)d_in[5];
    const float* lnt_g   = (const float*)d_in[6];
    const float* lnt_b   = (const float*)d_in[7];
    const float* ln2_g   = (const float*)d_in[8];
    const float* ln2_b   = (const float*)d_in[9];
    const float* lncls_g = (const float*)d_in[10];
    const float* lncls_b = (const float*)d_in[11];
    const float* Wqkv_s  = (const float*)d_in[12];
    const float* Wproj_s = (const float*)d_in[13];
    const float* bproj_s = (const float*)d_in[14];
    const float* Wqkv4   = (const float*)d_in[15];
    const float* Wqkv8   = (const float*)d_in[16];
    const float* Wqkv16  = (const float*)d_in[17];
    const float* Wp4     = (const float*)d_in[18];
    const float* bp4     = (const float*)d_in[19];
    const float* Wp8     = (const float*)d_in[20];
    const float* bp8     = (const float*)d_in[21];
    const float* Wp16    = (const float*)d_in[22];
    const float* bp16    = (const float*)d_in[23];
    const float* Wtfc    = (const float*)d_in[24];
    const float* btfc    = (const float*)d_in[25];
    const float* Wfc1    = (const float*)d_in[26];
    const float* bfc1    = (const float*)d_in[27];
    const float* Wfc2    = (const float*)d_in[28];
    const float* bfc2    = (const float*)d_in[29];
    float* out = (float*)d_out;

    // ---- workspace layout (bytes), lifetime-aliased; peak = 96,694,272 (known-good)
    const size_t oW0 = 0;               // weight slot 0 (4,718,592)
    const size_t oW1 = 4718592;         // weight slot 1 (4,718,592)
    const size_t oR1 = 9437184;         // xtn -> atts -> hln          (19,365,888)
    const size_t oR2 = 28803072;        // res_temp ; h1 spans R2..R3  (19,267,584)
    const size_t oR3 = 48070656;        // qkv chunks ; h1 tail        (29,048,832)
    const size_t oR4 = 77119488;        // att -> xsn -> res_sp        (19,365,888)
    const size_t oCL = 96485376;        // clsln fp32 (196,608)
    const size_t oCO = 96681984;        // clsout fp32 (12,288)
    const size_t NEED = 96694272;
    if (ws_size < NEED) return;
    char* ws = (char*)d_ws;

    BF16* w0       = (BF16*)(ws + oW0);
    BF16* w1       = (BF16*)(ws + oW1);
    BF16* xtn      = (BF16*)(ws + oR1);
    BF16* atts     = (BF16*)(ws + oR1);
    BF16* hln      = (BF16*)(ws + oR1);
    BF16* res_temp = (BF16*)(ws + oR2);
    BF16* h1       = (BF16*)(ws + oR2);   // 12548x1536 bf16 = 38,547,456 B (spans R2+R3 head)
    BF16* qkv      = (BF16*)(ws + oR3);
    BF16* att      = (BF16*)(ws + oR4);
    BF16* xsn      = (BF16*)(ws + oR4);
    BF16* res_sp   = (BF16*)(ws + oR4);
    float* clsln   = (float*)(ws + oCL);
    float* clsout  = (float*)(ws + oCO);

    // ---- temporal LN
    ln_kernel<0><<<12544, 256, 0, stream>>>(x, nullptr, nullptr, lnt_g, lnt_b, xtn, nullptr);

    // ---- scale 16 (2 row-chunks of 6272)
    wtrans<<<dim3(24, 72), 256, 0, stream>>>(Wqkv16, w0, 768, 2304);
    for (int c = 0; c < 2; ++c) {
        gemm_bf16<0, 0><<<dim3(18, 49), 256, 0, stream>>>(xtn + (size_t)c * 6272 * 768, w0, nullptr, nullptr, qkv, 6272, 2304, 768);
        temporal_attn<16, 256><<<4704, 256, 0, stream>>>(qkv, att + (size_t)c * 6272 * 768);
    }
    wtrans<<<dim3(24, 24), 256, 0, stream>>>(Wp16, w1, 768, 768);
    gemm_bf16<0, 1><<<dim3(6, 98), 256, 0, stream>>>(att, w1, bp16, nullptr, res_temp, 12544, 768, 768);

    // ---- scale 8
    wtrans<<<dim3(24, 72), 256, 0, stream>>>(Wqkv8, w0, 768, 2304);
    gemm_bf16<1, 0><<<dim3(18, 49), 256, 0, stream>>>(xtn, w0, nullptr, nullptr, qkv, 6272, 2304, 768);
    temporal_attn<8, 64><<<9408, 64, 0, stream>>>(qkv, att);
    wtrans<<<dim3(24, 24), 256, 0, stream>>>(Wp8, w1, 768, 768);
    gemm_bf16<0, 2><<<dim3(6, 49), 256, 0, stream>>>(att, w1, bp8, nullptr, res_temp, 6272, 768, 768);

    // ---- scale 4
    wtrans<<<dim3(24, 72), 256, 0, stream>>>(Wqkv4, w0, 768, 2304);
    gemm_bf16<2, 0><<<dim3(18, 25), 256, 0, stream>>>(xtn, w0, nullptr, nullptr, qkv, 3136, 2304, 768);
    temporal_attn<4, 64><<<9408, 64, 0, stream>>>(qkv, att);
    wtrans<<<dim3(24, 24), 256, 0, stream>>>(Wp4, w1, 768, 768);
    gemm_bf16<0, 3><<<dim3(6, 25), 256, 0, stream>>>(att, w1, bp4, nullptr, res_temp, 3136, 768, 768);

    // ---- temporal FC + x residual -> xtfull stored in d_out at x-like rows
    wtrans<<<dim3(24, 24), 256, 0, stream>>>(Wtfc, w0, 768, 768);
    gemm_bf16<0, 4><<<dim3(6, 98), 256, 0, stream>>>(res_temp, w0, btfc, x, out, 12544, 768, 768);

    // ---- spatial path (2 chunks of 32 bt-groups = 6304 rows)
    ln_kernel<1><<<12608, 256, 0, stream>>>(x, out, nullptr, ln1_g, ln1_b, xsn, nullptr);
    wtrans<<<dim3(24, 72), 256, 0, stream>>>(Wqkv_s, w1, 768, 2304);
    for (int c = 0; c < 2; ++c) {
        gemm_bf16<0, 0><<<dim3(18, 50), 256, 0, stream>>>(xsn + (size_t)c * 6304 * 768, w1, nullptr, nullptr, qkv, 6304, 2304, 768);
        spatial_attn_mfma<<<1536, 256, 0, stream>>>(qkv, atts + (size_t)c * 6304 * 768);
    }
    wtrans<<<dim3(24, 24), 256, 0, stream>>>(Wproj_s, w0, 768, 768);
    gemm_bf16<0, 1><<<dim3(6, 99), 256, 0, stream>>>(atts, w0, bproj_s, nullptr, res_sp, 12608, 768, 768);

    // ---- cls path
    ln_kernel<3><<<64, 256, 0, stream>>>(nullptr, nullptr, res_sp, lncls_g, lncls_b, nullptr, clsln);
    cls_attn_kernel<<<4, 256, 0, stream>>>(clsln, clsout);

    // ---- combine + ln2 fused (in-place x_cat in d_out, hln bf16 out)
    xcat_ln_kernel<<<12548, 256, 0, stream>>>(x, res_sp, clsout, ln2_g, ln2_b, out, hln);

    // ---- MLP: full-M, hidden split in 2 halves; fc2 accumulates into d_out
    wtrans<<<dim3(24, 96), 256, 0, stream>>>(Wfc1, w0, 768, 3072);          // w0 = Wfc1t [3072,768]
    wtrans<<<dim3(48, 24), 256, 0, stream>>>(Wfc2, w1, 1536, 768);          // w1a [768,1536]
    wtrans<<<dim3(48, 24), 256, 0, stream>>>(Wfc2 + (size_t)1536 * 768, w1 + (size_t)768 * 1536, 1536, 768);  // w1b

    // half a
    gemm_bf16<0, 6><<<dim3(12, 99), 256, 0, stream>>>(hln, w0, bfc1, nullptr, h1, 12548, 1536, 768);
    gemm_bf16<0, 7><<<dim3(6, 99), 256, 0, stream>>>(h1, w1, bfc2, out, out, 12548, 768, 1536);
    // half b
    gemm_bf16<0, 6><<<dim3(12, 99), 256, 0, stream>>>(hln, w0 + (size_t)1536 * 768, bfc1 + 1536, nullptr, h1, 12548, 1536, 768);
    gemm_bf16<0, 8><<<dim3(6, 99), 256, 0, stream>>>(h1, w1 + (size_t)768 * 1536, nullptr, out, out, 12548, 768, 1536);
}

// Round 7
// 1031.740 us; speedup vs baseline: 1.2140x; 1.0154x over previous
//
#include <hip/hip_runtime.h>
#include <hip/hip_bf16.h>
#include <stdint.h>

#define BF16 __hip_bfloat16

typedef __attribute__((ext_vector_type(8))) short short8;
typedef __attribute__((ext_vector_type(2))) short short2v;
typedef __attribute__((ext_vector_type(4))) float floatx4;

typedef const __attribute__((address_space(1))) void* gas_cvp;
typedef __attribute__((address_space(3))) void* las_vp;

__device__ __forceinline__ float bf2f(BF16 v) { return __bfloat162float(v); }
__device__ __forceinline__ BF16 f2bf(float v) { return __float2bfloat16(v); }

// ---------------------------------------------------------------------------
// Weight fp32 [K,N] -> bf16 transposed [N,K]  (single-weight fallback)
// ---------------------------------------------------------------------------
__global__ __launch_bounds__(256) void wtrans(const float* __restrict__ W,
                                              BF16* __restrict__ Wt, int K, int N) {
    __shared__ float t[32][33];
    int k0 = blockIdx.x * 32, n0 = blockIdx.y * 32;
    int tx = threadIdx.x & 31, ty = threadIdx.x >> 5;  // ty 0..7
#pragma unroll
    for (int i = 0; i < 32; i += 8) t[ty + i][tx] = W[(size_t)(k0 + ty + i) * N + n0 + tx];
    __syncthreads();
#pragma unroll
    for (int i = 0; i < 32; i += 8)
        Wt[(size_t)(n0 + ty + i) * K + k0 + tx] = f2bf(t[tx][ty + i]);
}

// ---------------------------------------------------------------------------
// Batched weight transpose: all 12 jobs in one dispatch (removes ~10 small
// launches from the serial dependency chain).
// ---------------------------------------------------------------------------
struct WTJob { const float* src; BF16* dst; int K; int N; int boff; };
struct WTParams { WTJob j[12]; };

__global__ __launch_bounds__(256) void wtrans_all(WTParams P) {
    __shared__ float t[32][33];
    const int bid = blockIdx.x;
    int ji = 0;
#pragma unroll
    for (int i = 1; i < 12; ++i)
        if (bid >= P.j[i].boff) ji = i;
    const float* __restrict__ W = P.j[ji].src;
    BF16* __restrict__ Wt = P.j[ji].dst;
    const int K = P.j[ji].K, N = P.j[ji].N;
    const int lb = bid - P.j[ji].boff;
    const int kb = K >> 5;
    const int k0 = (lb % kb) * 32, n0 = (lb / kb) * 32;
    const int tx = threadIdx.x & 31, ty = threadIdx.x >> 5;
#pragma unroll
    for (int i = 0; i < 32; i += 8) t[ty + i][tx] = W[(size_t)(k0 + ty + i) * N + n0 + tx];
    __syncthreads();
#pragma unroll
    for (int i = 0; i < 32; i += 8)
        Wt[(size_t)(n0 + ty + i) * K + k0 + tx] = f2bf(t[tx][ty + i]);
}

// ---------------------------------------------------------------------------
// LayerNorm over 768 cols, block=256.
// MODE 0: rows of x[:,1:,:]  -> bf16
// MODE 1: spatial xs rows (cls from x fp32 / patch from xtfull-in-dout) -> bf16
// ---------------------------------------------------------------------------
template <int MODE>
__global__ __launch_bounds__(256) void ln_kernel(const float* __restrict__ src0,
                                                 const float* __restrict__ src1,
                                                 const BF16* __restrict__ srcb,
                                                 const float* __restrict__ g,
                                                 const float* __restrict__ bta,
                                                 BF16* __restrict__ dst_bf,
                                                 float* __restrict__ dst_f) {
    const int r = blockIdx.x, tid = threadIdx.x;
    float x0, x1, x2;
    {
        const float* src;
        if (MODE == 0) {
            int b = r / 3136, rr = r - b * 3136;
            src = src0 + ((size_t)b * 3137 + 1 + rr) * 768;
        } else if (MODE == 1) {
            int bt = r / 197, j = r - bt * 197;
            int b = bt >> 4, t = bt & 15;
            if (j == 0) src = src0 + (size_t)b * 3137 * 768;
            else        src = src1 + ((size_t)(b * 3137 + 1) + (size_t)(j - 1) * 16 + t) * 768;
        } else {
            src = src0 + (size_t)r * 768;
        }
        x0 = src[tid]; x1 = src[tid + 256]; x2 = src[tid + 512];
    }
    float s = x0 + x1 + x2;
    float ss = x0 * x0 + x1 * x1 + x2 * x2;
    __shared__ float red[8];
#pragma unroll
    for (int o = 32; o > 0; o >>= 1) { s += __shfl_down(s, o); ss += __shfl_down(ss, o); }
    if ((tid & 63) == 0) { red[tid >> 6] = s; red[4 + (tid >> 6)] = ss; }
    __syncthreads();
    s = red[0] + red[1] + red[2] + red[3];
    ss = red[4] + red[5] + red[6] + red[7];
    const float mu = s * (1.0f / 768.0f);
    const float var = ss * (1.0f / 768.0f) - mu * mu;
    const float rstd = rsqrtf(var + 1e-5f);
#pragma unroll
    for (int i = 0; i < 3; ++i) {
        int c = tid + i * 256;
        float xv = (i == 0) ? x0 : (i == 1) ? x1 : x2;
        float y = (xv - mu) * rstd * g[c] + bta[c];
        dst_bf[(size_t)r * 768 + c] = f2bf(y);
    }
}

// ---------------------------------------------------------------------------
// bf16 GEMM: C[M,N] = A'[M,K] @ Bt[N,K]^T with row-mapped A and fused epilogue.
// BK=64, XOR-swizzled LDS k-blocks (phys = logical ^ (row&7)), grid x=N-tiles.
// XCD-chunked bijective block swizzle (R1-verified: FETCH 80->29MB, fc1 94->67us).
// AMAP: 0 identity; 1 scale8; 2 scale4
// OMODE: 0 bf16 plain; 1 bf16 +bias; 2 merge8 RMW; 3 merge4 RMW;
//        4 fp32 +bias +x-residual at CLS-skip row; 6 bf16 +bias+gelu;
//        7 fp32 +bias+res(in-place ok); 8 fp32 +res accumulate
// ---------------------------------------------------------------------------
template <int AMAP, int OMODE>
__global__ __launch_bounds__(256) void gemm_bf16(const BF16* __restrict__ A,
                                                 const BF16* __restrict__ Bt,
                                                 const float* __restrict__ bias,
                                                 const void* res,
                                                 void* Cout,
                                                 int M, int N, int K) {
    __shared__ BF16 Al[128 * 64];
    __shared__ BF16 Bl[128 * 64];
    const int tid = threadIdx.x;
    const int lane = tid & 63;
    const int w = tid >> 6;

    const int gx = gridDim.x;
    const int nwg = gx * (int)gridDim.y;
    const int orig = (int)blockIdx.y * gx + (int)blockIdx.x;
    const int xcd = orig & 7;
    const int idx = orig >> 3;
    const int q8 = nwg >> 3, r8 = nwg & 7;
    const int wgid = (xcd < r8 ? xcd * (q8 + 1) : r8 * (q8 + 1) + (xcd - r8) * q8) + idx;
    const int bn0 = (wgid % gx) * 128;  // N-tile fast-varying: chunk-mates share A
    const int bm0 = (wgid / gx) * 128;

    // staging: 32 chunks (16 A + 16 B) of 8 rows x 128 B; wave w owns 8 chunks.
    // lane -> (row-in-chunk, phys k-block); fetch logical block phys^row for swizzle.
    const BF16* gsrc[8];
    BF16* ldst[8];
    const int rin = lane >> 3;
    const int kblk = (lane & 7) ^ rin;
#pragma unroll
    for (int j = 0; j < 8; ++j) {
        int c = w * 8 + j;
        if (c < 16) {
            int gr = bm0 + c * 8 + rin;
            if (gr > M - 1) gr = M - 1;
            if (AMAP == 1) gr = (gr >> 3) * 16 + 8 + (gr & 7);
            if (AMAP == 2) gr = (gr >> 2) * 16 + 12 + (gr & 3);
            gsrc[j] = A + (size_t)gr * K + kblk * 8;
            ldst[j] = Al + c * 512;
        } else {
            int gn = bn0 + (c - 16) * 8 + rin;
            gsrc[j] = Bt + (size_t)gn * K + kblk * 8;
            ldst[j] = Bl + (c - 16) * 512;
        }
    }

    const int wm = (w & 1) * 64;
    const int wn = (w >> 1) * 64;
    const int fr = lane & 15;
    const int fq = lane >> 4;
    const int sw = fr & 7;
    const int o0 = (fq ^ sw) * 8;        // k-half 0: logical block fq
    const int o1 = ((fq + 4) ^ sw) * 8;  // k-half 1: logical block fq+4
    const BF16* pa[4];
    const BF16* pb[4];
#pragma unroll
    for (int t = 0; t < 4; ++t) {
        pa[t] = Al + (wm + t * 16 + fr) * 64;
        pb[t] = Bl + (wn + t * 16 + fr) * 64;
    }

    floatx4 acc[4][4];
#pragma unroll
    for (int i = 0; i < 4; ++i)
#pragma unroll
        for (int j = 0; j < 4; ++j) acc[i][j] = (floatx4){0.f, 0.f, 0.f, 0.f};

    for (int k0 = 0; k0 < K; k0 += 64) {
#pragma unroll
        for (int j = 0; j < 8; ++j) {
            __builtin_amdgcn_global_load_lds((gas_cvp)gsrc[j], (las_vp)ldst[j], 16, 0, 0);
            gsrc[j] += 64;
        }
        __syncthreads();
        {
            short8 af[4], bfr[4];
#pragma unroll
            for (int t = 0; t < 4; ++t) {
                af[t] = *(const short8*)(pa[t] + o0);
                bfr[t] = *(const short8*)(pb[t] + o0);
            }
#pragma unroll
            for (int mt = 0; mt < 4; ++mt)
#pragma unroll
                for (int nt = 0; nt < 4; ++nt)
                    acc[mt][nt] = __builtin_amdgcn_mfma_f32_16x16x32_bf16(af[mt], bfr[nt], acc[mt][nt], 0, 0, 0);
#pragma unroll
            for (int t = 0; t < 4; ++t) {
                af[t] = *(const short8*)(pa[t] + o1);
                bfr[t] = *(const short8*)(pb[t] + o1);
            }
#pragma unroll
            for (int mt = 0; mt < 4; ++mt)
#pragma unroll
                for (int nt = 0; nt < 4; ++nt)
                    acc[mt][nt] = __builtin_amdgcn_mfma_f32_16x16x32_bf16(af[mt], bfr[nt], acc[mt][nt], 0, 0, 0);
        }
        __syncthreads();
    }

#pragma unroll
    for (int mt = 0; mt < 4; ++mt) {
#pragma unroll
        for (int nt = 0; nt < 4; ++nt) {
            const int gcol = bn0 + wn + nt * 16 + fr;
#pragma unroll
            for (int r = 0; r < 4; ++r) {
                const int grow = bm0 + wm + mt * 16 + fq * 4 + r;
                if (grow < M) {
                    float v = acc[mt][nt][r];
                    if (OMODE != 0 && OMODE != 8) v += bias[gcol];
                    if (OMODE == 0 || OMODE == 1) {
                        ((BF16*)Cout)[(size_t)grow * N + gcol] = f2bf(v);
                    } else if (OMODE == 2) {
                        int t8 = grow & 7;
                        int rr = (grow >> 3) * 16 + 8 + t8;
                        float w8 = (t8 < 4) ? 0.5f : 0.25f;
                        BF16* R = (BF16*)Cout;
                        size_t o = (size_t)rr * 768 + gcol;
                        R[o] = f2bf(0.5f * bf2f(R[o]) + w8 * v);
                    } else if (OMODE == 3) {
                        int t4 = grow & 3;
                        int rr = (grow >> 2) * 16 + 12 + t4;
                        BF16* R = (BF16*)Cout;
                        size_t o = (size_t)rr * 768 + gcol;
                        R[o] = f2bf(bf2f(R[o]) + 0.25f * v);
                    } else if (OMODE == 4) {
                        int b = grow / 3136;
                        size_t xrow = (size_t)b * 3137 + 1 + (grow - b * 3136);
                        ((float*)Cout)[xrow * 768 + gcol] =
                            v + ((const float*)res)[xrow * 768 + gcol];
                    } else if (OMODE == 6) {
                        // fast GELU: x*sigmoid(2*0.7978845608*(x+0.044715x^3))
                        float u = v * (0.7978845608f + 0.0356774081f * v * v);
                        v = v / (1.0f + __expf(-2.0f * u));
                        ((BF16*)Cout)[(size_t)grow * N + gcol] = f2bf(v);
                    } else {  // 7, 8
                        v += ((const float*)res)[(size_t)grow * N + gcol];
                        ((float*)Cout)[(size_t)grow * N + gcol] = v;
                    }
                }
            }
        }
    }
}

// ---------------------------------------------------------------------------
// Temporal attention, one block per (group, head). L in {4,8,16}, d=64.
// ---------------------------------------------------------------------------
template <int L, int NT>
__global__ __launch_bounds__(NT) void temporal_attn(const BF16* __restrict__ qkv,
                                                    BF16* __restrict__ outp) {
    __shared__ float q[L * 64];
    __shared__ float k[L * 65];
    __shared__ float v[L * 64];
    __shared__ float S[L * L];
    const int bh = blockIdx.x;
    const int b = bh / 12, h = bh % 12;
    const int tid = threadIdx.x;
    const size_t rb = (size_t)b * L;
    for (int idx = tid; idx < L * 64; idx += NT) {
        int i = idx >> 6, d = idx & 63;
        size_t base = (rb + i) * 2304 + h * 64 + d;
        q[i * 64 + d] = bf2f(qkv[base]);
        k[i * 65 + d] = bf2f(qkv[base + 768]);
        v[i * 64 + d] = bf2f(qkv[base + 1536]);
    }
    __syncthreads();
    for (int idx = tid; idx < L * L; idx += NT) {
        int i = idx / L, j = idx % L;
        float a = 0.f;
#pragma unroll
        for (int d = 0; d < 64; ++d) a += q[i * 64 + d] * k[j * 65 + d];
        S[idx] = a * 0.125f;
    }
    __syncthreads();
    if (tid < L) {
        float mx = -1e30f;
        for (int j = 0; j < L; ++j) mx = fmaxf(mx, S[tid * L + j]);
        float sm = 0.f;
        for (int j = 0; j < L; ++j) { float e = __expf(S[tid * L + j] - mx); S[tid * L + j] = e; sm += e; }
        float inv = 1.0f / sm;
        for (int j = 0; j < L; ++j) S[tid * L + j] *= inv;
    }
    __syncthreads();
    for (int idx = tid; idx < L * 64; idx += NT) {
        int i = idx >> 6, d = idx & 63;
        float acc = 0.f;
#pragma unroll
        for (int j = 0; j < L; ++j) acc += S[i * L + j] * v[j * 64 + d];
        outp[(rb + i) * 768 + h * 64 + d] = f2bf(acc);
    }
}

// ---------------------------------------------------------------------------
// MFMA spatial attention. Block = (bt, h, qtile-of-64); 4 waves x 16 queries.
// ---------------------------------------------------------------------------
__global__ __launch_bounds__(256) void spatial_attn_mfma(const BF16* __restrict__ qkv,
                                                         BF16* __restrict__ outp) {
    const int bid = blockIdx.x;
    const int qt = bid & 3;
    const int h = (bid >> 2) % 12;
    const int bt = bid / 48;
    const int rowbase = bt * 197;
    __shared__ BF16 Ks[208 * 72];
    __shared__ BF16 Vt[64 * 232];
    __shared__ BF16 Pl[4][16 * 232];
    const int tid = threadIdx.x;
    const int lane = tid & 63;
    const int w = tid >> 6;
    const int ln = lane & 15;
    const int quad = lane >> 4;

    for (int it = tid; it < 208 * 8; it += 256) {
        int key = it >> 3, c = it & 7;
        int kc = key < 197 ? key : 196;
        short8 gk = *(const short8*)(qkv + (size_t)(rowbase + kc) * 2304 + 768 + h * 64 + c * 8);
        *(short8*)&Ks[key * 72 + c * 8] = gk;
    }
    for (int it = tid; it < 112 * 8; it += 256) {
        int p = it >> 3, c = it & 7;
        int kc0 = (2 * p < 197) ? 2 * p : 196;
        int kc1 = (2 * p + 1 < 197) ? 2 * p + 1 : 196;
        short8 a = *(const short8*)(qkv + (size_t)(rowbase + kc0) * 2304 + 1536 + h * 64 + c * 8);
        short8 b = *(const short8*)(qkv + (size_t)(rowbase + kc1) * 2304 + 1536 + h * 64 + c * 8);
#pragma unroll
        for (int e = 0; e < 8; ++e) {
            short2v pr;
            pr[0] = a[e];
            pr[1] = b[e];
            *(short2v*)&Vt[(c * 8 + e) * 232 + 2 * p] = pr;
        }
    }
    __syncthreads();

    const int m0 = qt * 64 + w * 16;
    int qrow = m0 + ln; if (qrow > 196) qrow = 196;
    const BF16* qptr = qkv + (size_t)(rowbase + qrow) * 2304 + h * 64 + quad * 8;
    short8 aq0 = *(const short8*)(qptr);
    short8 aq1 = *(const short8*)(qptr + 32);

    floatx4 sacc[13];
#pragma unroll
    for (int nt = 0; nt < 13; ++nt) sacc[nt] = (floatx4){0.f, 0.f, 0.f, 0.f};
#pragma unroll
    for (int nt = 0; nt < 13; ++nt) {
        const BF16* kb = &Ks[(nt * 16 + ln) * 72 + quad * 8];
        short8 b0 = *(const short8*)kb;
        short8 b1 = *(const short8*)(kb + 32);
        sacc[nt] = __builtin_amdgcn_mfma_f32_16x16x32_bf16(aq0, b0, sacc[nt], 0, 0, 0);
        sacc[nt] = __builtin_amdgcn_mfma_f32_16x16x32_bf16(aq1, b1, sacc[nt], 0, 0, 0);
    }

#pragma unroll
    for (int r = 0; r < 4; ++r) {
        float mx = -1e30f;
#pragma unroll
        for (int nt = 0; nt < 13; ++nt) {
            float s = sacc[nt][r] * 0.125f;
            sacc[nt][r] = s;
            if (nt * 16 + ln < 197) mx = fmaxf(mx, s);
        }
        mx = fmaxf(mx, __shfl_xor(mx, 1));
        mx = fmaxf(mx, __shfl_xor(mx, 2));
        mx = fmaxf(mx, __shfl_xor(mx, 4));
        mx = fmaxf(mx, __shfl_xor(mx, 8));
        float sum = 0.f;
#pragma unroll
        for (int nt = 0; nt < 13; ++nt) {
            float e = (nt * 16 + ln < 197) ? __expf(sacc[nt][r] - mx) : 0.f;
            sacc[nt][r] = e;
            sum += e;
        }
        sum += __shfl_xor(sum, 1);
        sum += __shfl_xor(sum, 2);
        sum += __shfl_xor(sum, 4);
        sum += __shfl_xor(sum, 8);
        float inv = 1.0f / sum;
#pragma unroll
        for (int nt = 0; nt < 13; ++nt) sacc[nt][r] *= inv;
    }

    BF16* pw = Pl[w];
#pragma unroll
    for (int nt = 0; nt < 13; ++nt)
#pragma unroll
        for (int r = 0; r < 4; ++r)
            pw[(quad * 4 + r) * 232 + nt * 16 + ln] = f2bf(sacc[nt][r]);
#pragma unroll
    for (int r = 0; r < 4; ++r)
        pw[(quad * 4 + r) * 232 + 208 + ln] = f2bf(0.f);

    floatx4 oacc[4];
#pragma unroll
    for (int nt = 0; nt < 4; ++nt) oacc[nt] = (floatx4){0.f, 0.f, 0.f, 0.f};
    for (int kb = 0; kb < 7; ++kb) {
        short8 ap = *(const short8*)&pw[ln * 232 + kb * 32 + quad * 8];
#pragma unroll
        for (int nt = 0; nt < 4; ++nt) {
            short8 bv = *(const short8*)&Vt[(nt * 16 + ln) * 232 + kb * 32 + quad * 8];
            oacc[nt] = __builtin_amdgcn_mfma_f32_16x16x32_bf16(ap, bv, oacc[nt], 0, 0, 0);
        }
    }

#pragma unroll
    for (int nt = 0; nt < 4; ++nt) {
        int dim = nt * 16 + ln;
#pragma unroll
        for (int r = 0; r < 4; ++r) {
            int q = m0 + quad * 4 + r;
            if (q < 197)
                outp[(size_t)(rowbase + q) * 768 + h * 64 + dim] = f2bf(oacc[nt][r]);
        }
    }
}

// ---------------------------------------------------------------------------
// Fused cls path: LN (lncls) of the 16 cls rows of batch b into LDS, then the
// tiny second attention. Replaces ln_kernel<3> + cls_attn_kernel and drops
// the clsln global buffer.
// ---------------------------------------------------------------------------
__global__ __launch_bounds__(256) void cls_ln_attn_kernel(const BF16* __restrict__ res_sp,
                                                          const float* __restrict__ g,
                                                          const float* __restrict__ bta,
                                                          float* __restrict__ clsout) {
    const int b = blockIdx.x;  // 0..3
    const int tid = threadIdx.x;
    __shared__ float sLN[16][768];
    __shared__ float red[8];
    __shared__ float dots[16];
    __shared__ float aw[16];

    for (int t = 0; t < 16; ++t) {
        const BF16* src = res_sp + (size_t)((b * 16 + t) * 197) * 768;
        float x0 = bf2f(src[tid]);
        float x1 = bf2f(src[tid + 256]);
        float x2 = bf2f(src[tid + 512]);
        float s = x0 + x1 + x2;
        float ss = x0 * x0 + x1 * x1 + x2 * x2;
#pragma unroll
        for (int o = 32; o > 0; o >>= 1) { s += __shfl_down(s, o); ss += __shfl_down(ss, o); }
        if ((tid & 63) == 0) { red[tid >> 6] = s; red[4 + (tid >> 6)] = ss; }
        __syncthreads();
        s = red[0] + red[1] + red[2] + red[3];
        ss = red[4] + red[5] + red[6] + red[7];
        const float mu = s * (1.0f / 768.0f);
        const float var = ss * (1.0f / 768.0f) - mu * mu;
        const float rstd = rsqrtf(var + 1e-5f);
        sLN[t][tid]       = (x0 - mu) * rstd * g[tid] + bta[tid];
        sLN[t][tid + 256] = (x1 - mu) * rstd * g[tid + 256] + bta[tid + 256];
        sLN[t][tid + 512] = (x2 - mu) * rstd * g[tid + 512] + bta[tid + 512];
        __syncthreads();  // red reused next iteration; sLN row complete
    }

    const int t = tid >> 4, l16 = tid & 15;
    float p = 0.f;
    for (int c = l16; c < 768; c += 16) p += sLN[15][c] * sLN[t][c];
#pragma unroll
    for (int o = 8; o > 0; o >>= 1) p += __shfl_down(p, o, 16);
    if (l16 == 0) dots[t] = p;
    __syncthreads();
    if (tid == 0) {
        float mx = -1e30f;
        for (int j = 0; j < 16; ++j) mx = fmaxf(mx, dots[j]);
        float s = 0.f;
        for (int j = 0; j < 16; ++j) { aw[j] = __expf(dots[j] - mx); s += aw[j]; }
        float inv = 1.0f / s;
        for (int j = 0; j < 16; ++j) aw[j] *= inv;
    }
    __syncthreads();
    for (int c = tid; c < 768; c += 256) {
        float acc = 0.f;
#pragma unroll
        for (int j = 0; j < 16; ++j) acc += aw[j] * sLN[j][c];
        clsout[(size_t)b * 768 + c] = acc;
    }
}

// ---------------------------------------------------------------------------
// Fused x_cat build + ln2: row j=0 gets x_cls + cls_sp; rows j>=1 get
// (already-present xtfull) + x_s.  Writes fp32 x_cat to outbuf AND the
// LayerNorm'd bf16 row to hln.
// ---------------------------------------------------------------------------
__global__ __launch_bounds__(256) void xcat_ln_kernel(const float* __restrict__ x,
                                                      const BF16* __restrict__ res_sp,
                                                      const float* __restrict__ clsout,
                                                      const float* __restrict__ g,
                                                      const float* __restrict__ bta,
                                                      float* outbuf,
                                                      BF16* __restrict__ hln) {
    const int gidx = blockIdx.x;
    const int b = gidx / 3137, j = gidx - b * 3137;
    const int tid = threadIdx.x;
    float v0, v1, v2;
    if (j == 0) {
        const float* xr = x + (size_t)b * 3137 * 768;
        const float* cr = clsout + (size_t)b * 768;
        v0 = xr[tid] + cr[tid];
        v1 = xr[tid + 256] + cr[tid + 256];
        v2 = xr[tid + 512] + cr[tid + 512];
    } else {
        const int p = j - 1, k = p >> 4, t = p & 15;
        const BF16* rs = res_sp + (size_t)((b * 16 + t) * 197 + 1 + k) * 768;
        float* orow = outbuf + (size_t)gidx * 768;
        v0 = orow[tid] + bf2f(rs[tid]);
        v1 = orow[tid + 256] + bf2f(rs[tid + 256]);
        v2 = orow[tid + 512] + bf2f(rs[tid + 512]);
    }
    float* orow = outbuf + (size_t)gidx * 768;
    orow[tid] = v0; orow[tid + 256] = v1; orow[tid + 512] = v2;

    float s = v0 + v1 + v2;
    float ss = v0 * v0 + v1 * v1 + v2 * v2;
    __shared__ float red[8];
#pragma unroll
    for (int o = 32; o > 0; o >>= 1) { s += __shfl_down(s, o); ss += __shfl_down(ss, o); }
    if ((tid & 63) == 0) { red[tid >> 6] = s; red[4 + (tid >> 6)] = ss; }
    __syncthreads();
    s = red[0] + red[1] + red[2] + red[3];
    ss = red[4] + red[5] + red[6] + red[7];
    const float mu = s * (1.0f / 768.0f);
    const float var = ss * (1.0f / 768.0f) - mu * mu;
    const float rstd = rsqrtf(var + 1e-5f);
#pragma unroll
    for (int i = 0; i < 3; ++i) {
        int c = tid + i * 256;
        float xv = (i == 0) ? v0 : (i == 1) ? v1 : v2;
        hln[(size_t)gidx * 768 + c] = f2bf((xv - mu) * rstd * g[c] + bta[c]);
    }
}

// ---------------------------------------------------------------------------
extern "C" void kernel_launch(void* const* d_in, const int* in_sizes, int n_in,
                              void* d_out, int out_size, void* d_ws, size_t ws_size,
                              hipStream_t stream) {
    const float* x       = (const float*)d_in[0];
    const float* ln1_g   = (const float*)d_in[4];
    const float* ln1_b   = (const float*)d_in[5];
    const float* lnt_g   = (const float*)d_in[6];
    const float* lnt_b   = (const float*)d_in[7];
    const float* ln2_g   = (const float*)d_in[8];
    const float* ln2_b   = (const float*)d_in[9];
    const float* lncls_g = (const float*)d_in[10];
    const float* lncls_b = (const float*)d_in[11];
    const float* Wqkv_s  = (const float*)d_in[12];
    const float* Wproj_s = (const float*)d_in[13];
    const float* bproj_s = (const float*)d_in[14];
    const float* Wqkv4   = (const float*)d_in[15];
    const float* Wqkv8   = (const float*)d_in[16];
    const float* Wqkv16  = (const float*)d_in[17];
    const float* Wp4     = (const float*)d_in[18];
    const float* bp4     = (const float*)d_in[19];
    const float* Wp8     = (const float*)d_in[20];
    const float* bp8     = (const float*)d_in[21];
    const float* Wp16    = (const float*)d_in[22];
    const float* bp16    = (const float*)d_in[23];
    const float* Wtfc    = (const float*)d_in[24];
    const float* btfc    = (const float*)d_in[25];
    const float* Wfc1    = (const float*)d_in[26];
    const float* bfc1    = (const float*)d_in[27];
    const float* Wfc2    = (const float*)d_in[28];
    const float* bfc2    = (const float*)d_in[29];
    float* out = (float*)d_out;

    // ---- workspace layout (bytes), lifetime-aliased; base peak = 96,694,272
    const size_t oW0 = 0;               // weight slot 0 (4,718,592)
    const size_t oW1 = 4718592;         // weight slot 1 (4,718,592)
    const size_t oR1 = 9437184;         // xtn -> atts -> hln          (19,365,888)
    const size_t oR2 = 28803072;        // res_temp ; h1 spans R2..R3  (19,267,584)
    const size_t oR3 = 48070656;        // qkv chunks ; h1 tail        (29,048,832)
    const size_t oR4 = 77119488;        // att -> xsn -> res_sp        (19,365,888)
    const size_t oCO = 96681984;        // clsout fp32 (12,288)
    const size_t NEED = 96694272;
    // big mode: all transposed weights resident simultaneously (+29,491,200)
    const size_t NEED_BIG = NEED + 29491200;
    if (ws_size < NEED) return;
    char* ws = (char*)d_ws;

    BF16* w0       = (BF16*)(ws + oW0);
    BF16* w1       = (BF16*)(ws + oW1);
    BF16* xtn      = (BF16*)(ws + oR1);
    BF16* atts     = (BF16*)(ws + oR1);
    BF16* hln      = (BF16*)(ws + oR1);
    BF16* res_temp = (BF16*)(ws + oR2);
    BF16* h1       = (BF16*)(ws + oR2);   // 12548x1536 bf16 = 38,547,456 B
    BF16* qkv      = (BF16*)(ws + oR3);
    BF16* att      = (BF16*)(ws + oR4);
    BF16* xsn      = (BF16*)(ws + oR4);
    BF16* res_sp   = (BF16*)(ws + oR4);
    float* clsout  = (float*)(ws + oCO);

    const bool big = (ws_size >= NEED_BIG);
    BF16 *tqkv16, *tqkv8, *tqkv4, *tqkvs, *tp16, *tp8, *tp4, *ttfc, *tproj, *tfc1, *tfc2;
    if (big) {
        char* wx = ws + NEED;
        tqkv16 = (BF16*)wx; wx += 3538944;
        tqkv8  = (BF16*)wx; wx += 3538944;
        tqkv4  = (BF16*)wx; wx += 3538944;
        tqkvs  = (BF16*)wx; wx += 3538944;
        tp16   = (BF16*)wx; wx += 1179648;
        tp8    = (BF16*)wx; wx += 1179648;
        tp4    = (BF16*)wx; wx += 1179648;
        ttfc   = (BF16*)wx; wx += 1179648;
        tproj  = (BF16*)wx; wx += 1179648;
        tfc1   = (BF16*)wx; wx += 4718592;
        tfc2   = (BF16*)wx; wx += 4718592;
        WTParams P;
        P.j[0]  = { Wqkv16,                     tqkv16,                     768, 2304,     0 };
        P.j[1]  = { Wqkv8,                      tqkv8,                      768, 2304,  1728 };
        P.j[2]  = { Wqkv4,                      tqkv4,                      768, 2304,  3456 };
        P.j[3]  = { Wqkv_s,                     tqkvs,                      768, 2304,  5184 };
        P.j[4]  = { Wp16,                       tp16,                       768,  768,  6912 };
        P.j[5]  = { Wp8,                        tp8,                        768,  768,  7488 };
        P.j[6]  = { Wp4,                        tp4,                        768,  768,  8064 };
        P.j[7]  = { Wtfc,                       ttfc,                       768,  768,  8640 };
        P.j[8]  = { Wproj_s,                    tproj,                      768,  768,  9216 };
        P.j[9]  = { Wfc1,                       tfc1,                       768, 3072,  9792 };
        P.j[10] = { Wfc2,                       tfc2,                      1536,  768, 12096 };
        P.j[11] = { Wfc2 + (size_t)1536 * 768,  tfc2 + (size_t)768 * 1536, 1536,  768, 13248 };
        wtrans_all<<<14400, 256, 0, stream>>>(P);
    } else {
        // fallback: just-in-time transposes into the two rotating slots
        tqkv16 = w0; tqkv8 = w0; tqkv4 = w0; tqkvs = w1;
        tp16 = w1; tp8 = w1; tp4 = w1; ttfc = w0; tproj = w0;
        tfc1 = w0; tfc2 = w1;
    }

    // ---- temporal LN
    ln_kernel<0><<<12544, 256, 0, stream>>>(x, nullptr, nullptr, lnt_g, lnt_b, xtn, nullptr);

    // ---- scale 16 (2 row-chunks of 6272)
    if (!big) wtrans<<<dim3(24, 72), 256, 0, stream>>>(Wqkv16, tqkv16, 768, 2304);
    for (int c = 0; c < 2; ++c) {
        gemm_bf16<0, 0><<<dim3(18, 49), 256, 0, stream>>>(xtn + (size_t)c * 6272 * 768, tqkv16, nullptr, nullptr, qkv, 6272, 2304, 768);
        temporal_attn<16, 256><<<4704, 256, 0, stream>>>(qkv, att + (size_t)c * 6272 * 768);
    }
    if (!big) wtrans<<<dim3(24, 24), 256, 0, stream>>>(Wp16, tp16, 768, 768);
    gemm_bf16<0, 1><<<dim3(6, 98), 256, 0, stream>>>(att, tp16, bp16, nullptr, res_temp, 12544, 768, 768);

    // ---- scale 8
    if (!big) wtrans<<<dim3(24, 72), 256, 0, stream>>>(Wqkv8, tqkv8, 768, 2304);
    gemm_bf16<1, 0><<<dim3(18, 49), 256, 0, stream>>>(xtn, tqkv8, nullptr, nullptr, qkv, 6272, 2304, 768);
    temporal_attn<8, 64><<<9408, 64, 0, stream>>>(qkv, att);
    if (!big) wtrans<<<dim3(24, 24), 256, 0, stream>>>(Wp8, tp8, 768, 768);
    gemm_bf16<0, 2><<<dim3(6, 49), 256, 0, stream>>>(att, tp8, bp8, nullptr, res_temp, 6272, 768, 768);

    // ---- scale 4
    if (!big) wtrans<<<dim3(24, 72), 256, 0, stream>>>(Wqkv4, tqkv4, 768, 2304);
    gemm_bf16<2, 0><<<dim3(18, 25), 256, 0, stream>>>(xtn, tqkv4, nullptr, nullptr, qkv, 3136, 2304, 768);
    temporal_attn<4, 64><<<9408, 64, 0, stream>>>(qkv, att);
    if (!big) wtrans<<<dim3(24, 24), 256, 0, stream>>>(Wp4, tp4, 768, 768);
    gemm_bf16<0, 3><<<dim3(6, 25), 256, 0, stream>>>(att, tp4, bp4, nullptr, res_temp, 3136, 768, 768);

    // ---- temporal FC + x residual -> xtfull stored in d_out at x-like rows
    if (!big) wtrans<<<dim3(24, 24), 256, 0, stream>>>(Wtfc, ttfc, 768, 768);
    gemm_bf16<0, 4><<<dim3(6, 98), 256, 0, stream>>>(res_temp, ttfc, btfc, x, out, 12544, 768, 768);

    // ---- spatial path (2 chunks of 32 bt-groups = 6304 rows)
    ln_kernel<1><<<12608, 256, 0, stream>>>(x, out, nullptr, ln1_g, ln1_b, xsn, nullptr);
    if (!big) wtrans<<<dim3(24, 72), 256, 0, stream>>>(Wqkv_s, tqkvs, 768, 2304);
    for (int c = 0; c < 2; ++c) {
        gemm_bf16<0, 0><<<dim3(18, 50), 256, 0, stream>>>(xsn + (size_t)c * 6304 * 768, tqkvs, nullptr, nullptr, qkv, 6304, 2304, 768);
        spatial_attn_mfma<<<1536, 256, 0, stream>>>(qkv, atts + (size_t)c * 6304 * 768);
    }
    if (!big) wtrans<<<dim3(24, 24), 256, 0, stream>>>(Wproj_s, tproj, 768, 768);
    gemm_bf16<0, 1><<<dim3(6, 99), 256, 0, stream>>>(atts, tproj, bproj_s, nullptr, res_sp, 12608, 768, 768);

    // ---- cls path (fused LN + attention)
    cls_ln_attn_kernel<<<4, 256, 0, stream>>>(res_sp, lncls_g, lncls_b, clsout);

    // ---- combine + ln2 fused (in-place x_cat in d_out, hln bf16 out)
    xcat_ln_kernel<<<12548, 256, 0, stream>>>(x, res_sp, clsout, ln2_g, ln2_b, out, hln);

    // ---- MLP: full-M, hidden split in 2 halves; fc2 accumulates into d_out
    if (!big) {
        wtrans<<<dim3(24, 96), 256, 0, stream>>>(Wfc1, tfc1, 768, 3072);
        wtrans<<<dim3(48, 24), 256, 0, stream>>>(Wfc2, tfc2, 1536, 768);
        wtrans<<<dim3(48, 24), 256, 0, stream>>>(Wfc2 + (size_t)1536 * 768, tfc2 + (size_t)768 * 1536, 1536, 768);
    }

    // half a
    gemm_bf16<0, 6><<<dim3(12, 99), 256, 0, stream>>>(hln, tfc1, bfc1, nullptr, h1, 12548, 1536, 768);
    gemm_bf16<0, 7><<<dim3(6, 99), 256, 0, stream>>>(h1, tfc2, bfc2, out, out, 12548, 768, 1536);
    // half b
    gemm_bf16<0, 6><<<dim3(12, 99), 256, 0, stream>>>(hln, tfc1 + (size_t)1536 * 768, bfc1 + 1536, nullptr, h1, 12548, 1536, 768);
    gemm_bf16<0, 8><<<dim3(6, 99), 256, 0, stream>>>(h1, tfc2 + (size_t)768 * 1536, nullptr, out, out, 12548, 768, 1536);
}

// Round 9
// 942.506 us; speedup vs baseline: 1.3289x; 1.0947x over previous
//
#include <hip/hip_runtime.h>
#include <hip/hip_bf16.h>
#include <stdint.h>

#define BF16 __hip_bfloat16

typedef __attribute__((ext_vector_type(8))) short short8;
typedef __attribute__((ext_vector_type(2))) short short2v;
typedef __attribute__((ext_vector_type(4))) float floatx4;

typedef const __attribute__((address_space(1))) void* gas_cvp;
typedef __attribute__((address_space(3))) void* las_vp;

__device__ __forceinline__ float bf2f(BF16 v) { return __bfloat162float(v); }
__device__ __forceinline__ BF16 f2bf(float v) { return __float2bfloat16(v); }

// ---------------------------------------------------------------------------
// Weight fp32 [K,N] -> bf16 transposed [N,K]  (single-weight fallback)
// ---------------------------------------------------------------------------
__global__ __launch_bounds__(256) void wtrans(const float* __restrict__ W,
                                              BF16* __restrict__ Wt, int K, int N) {
    __shared__ float t[32][33];
    int k0 = blockIdx.x * 32, n0 = blockIdx.y * 32;
    int tx = threadIdx.x & 31, ty = threadIdx.x >> 5;  // ty 0..7
#pragma unroll
    for (int i = 0; i < 32; i += 8) t[ty + i][tx] = W[(size_t)(k0 + ty + i) * N + n0 + tx];
    __syncthreads();
#pragma unroll
    for (int i = 0; i < 32; i += 8)
        Wt[(size_t)(n0 + ty + i) * K + k0 + tx] = f2bf(t[tx][ty + i]);
}

// ---------------------------------------------------------------------------
// Batched weight transpose: all 12 jobs in one dispatch.
// ---------------------------------------------------------------------------
struct WTJob { const float* src; BF16* dst; int K; int N; int boff; };
struct WTParams { WTJob j[12]; };

__global__ __launch_bounds__(256) void wtrans_all(WTParams P) {
    __shared__ float t[32][33];
    const int bid = blockIdx.x;
    int ji = 0;
#pragma unroll
    for (int i = 1; i < 12; ++i)
        if (bid >= P.j[i].boff) ji = i;
    const float* __restrict__ W = P.j[ji].src;
    BF16* __restrict__ Wt = P.j[ji].dst;
    const int K = P.j[ji].K, N = P.j[ji].N;
    const int lb = bid - P.j[ji].boff;
    const int kb = K >> 5;
    const int k0 = (lb % kb) * 32, n0 = (lb / kb) * 32;
    const int tx = threadIdx.x & 31, ty = threadIdx.x >> 5;
#pragma unroll
    for (int i = 0; i < 32; i += 8) t[ty + i][tx] = W[(size_t)(k0 + ty + i) * N + n0 + tx];
    __syncthreads();
#pragma unroll
    for (int i = 0; i < 32; i += 8)
        Wt[(size_t)(n0 + ty + i) * K + k0 + tx] = f2bf(t[tx][ty + i]);
}

// ---------------------------------------------------------------------------
// LayerNorm over 768 cols, block=256.
// MODE 0: rows of x[:,1:,:]  -> bf16
// MODE 1: spatial xs rows (cls from x fp32 / patch from xtfull-in-dout) -> bf16
// ---------------------------------------------------------------------------
template <int MODE>
__global__ __launch_bounds__(256) void ln_kernel(const float* __restrict__ src0,
                                                 const float* __restrict__ src1,
                                                 const BF16* __restrict__ srcb,
                                                 const float* __restrict__ g,
                                                 const float* __restrict__ bta,
                                                 BF16* __restrict__ dst_bf,
                                                 float* __restrict__ dst_f) {
    const int r = blockIdx.x, tid = threadIdx.x;
    float x0, x1, x2;
    {
        const float* src;
        if (MODE == 0) {
            int b = r / 3136, rr = r - b * 3136;
            src = src0 + ((size_t)b * 3137 + 1 + rr) * 768;
        } else if (MODE == 1) {
            int bt = r / 197, j = r - bt * 197;
            int b = bt >> 4, t = bt & 15;
            if (j == 0) src = src0 + (size_t)b * 3137 * 768;
            else        src = src1 + ((size_t)(b * 3137 + 1) + (size_t)(j - 1) * 16 + t) * 768;
        } else {
            src = src0 + (size_t)r * 768;
        }
        x0 = src[tid]; x1 = src[tid + 256]; x2 = src[tid + 512];
    }
    float s = x0 + x1 + x2;
    float ss = x0 * x0 + x1 * x1 + x2 * x2;
    __shared__ float red[8];
#pragma unroll
    for (int o = 32; o > 0; o >>= 1) { s += __shfl_down(s, o); ss += __shfl_down(ss, o); }
    if ((tid & 63) == 0) { red[tid >> 6] = s; red[4 + (tid >> 6)] = ss; }
    __syncthreads();
    s = red[0] + red[1] + red[2] + red[3];
    ss = red[4] + red[5] + red[6] + red[7];
    const float mu = s * (1.0f / 768.0f);
    const float var = ss * (1.0f / 768.0f) - mu * mu;
    const float rstd = rsqrtf(var + 1e-5f);
#pragma unroll
    for (int i = 0; i < 3; ++i) {
        int c = tid + i * 256;
        float xv = (i == 0) ? x0 : (i == 1) ? x1 : x2;
        float y = (xv - mu) * rstd * g[c] + bta[c];
        dst_bf[(size_t)r * 768 + c] = f2bf(y);
    }
}

// ---------------------------------------------------------------------------
// bf16 GEMM body: C[M,N] = A'[M,K] @ Bt[N,K]^T, row-mapped A, fused epilogue.
// BK=64, XOR-swizzled LDS k-blocks, XCD-chunked bijective block swizzle.
// Shared by the single-job wrapper and the dual-job co-launch kernel.
// AMAP: 0 identity; 1 scale8; 2 scale4
// OMODE: 0 bf16; 1 bf16+bias; 2 merge8 RMW; 3 merge4 RMW; 4 fp32+bias+x-res;
//        6 bf16+bias+gelu; 7 fp32+bias+res; 8 fp32+res accumulate
// ---------------------------------------------------------------------------
template <int AMAP, int OMODE>
__device__ __forceinline__ void gemm_body(BF16* Al, BF16* Bl,
                                          int orig, int nwg, int gx,
                                          const BF16* __restrict__ A,
                                          const BF16* __restrict__ Bt,
                                          const float* __restrict__ bias,
                                          const void* res, void* Cout,
                                          int M, int N, int K) {
    const int tid = threadIdx.x;
    const int lane = tid & 63;
    const int w = tid >> 6;

    const int xcd = orig & 7;
    const int idx = orig >> 3;
    const int q8 = nwg >> 3, r8 = nwg & 7;
    const int wgid = (xcd < r8 ? xcd * (q8 + 1) : r8 * (q8 + 1) + (xcd - r8) * q8) + idx;
    const int bn0 = (wgid % gx) * 128;  // N-tile fast-varying: chunk-mates share A
    const int bm0 = (wgid / gx) * 128;

    const BF16* gsrc[8];
    BF16* ldst[8];
    const int rin = lane >> 3;
    const int kblk = (lane & 7) ^ rin;
#pragma unroll
    for (int j = 0; j < 8; ++j) {
        int c = w * 8 + j;
        if (c < 16) {
            int gr = bm0 + c * 8 + rin;
            if (gr > M - 1) gr = M - 1;
            if (AMAP == 1) gr = (gr >> 3) * 16 + 8 + (gr & 7);
            if (AMAP == 2) gr = (gr >> 2) * 16 + 12 + (gr & 3);
            gsrc[j] = A + (size_t)gr * K + kblk * 8;
            ldst[j] = Al + c * 512;
        } else {
            int gn = bn0 + (c - 16) * 8 + rin;
            gsrc[j] = Bt + (size_t)gn * K + kblk * 8;
            ldst[j] = Bl + (c - 16) * 512;
        }
    }

    const int wm = (w & 1) * 64;
    const int wn = (w >> 1) * 64;
    const int fr = lane & 15;
    const int fq = lane >> 4;
    const int sw = fr & 7;
    const int o0 = (fq ^ sw) * 8;
    const int o1 = ((fq + 4) ^ sw) * 8;
    const BF16* pa[4];
    const BF16* pb[4];
#pragma unroll
    for (int t = 0; t < 4; ++t) {
        pa[t] = Al + (wm + t * 16 + fr) * 64;
        pb[t] = Bl + (wn + t * 16 + fr) * 64;
    }

    floatx4 acc[4][4];
#pragma unroll
    for (int i = 0; i < 4; ++i)
#pragma unroll
        for (int j = 0; j < 4; ++j) acc[i][j] = (floatx4){0.f, 0.f, 0.f, 0.f};

    for (int k0 = 0; k0 < K; k0 += 64) {
#pragma unroll
        for (int j = 0; j < 8; ++j) {
            __builtin_amdgcn_global_load_lds((gas_cvp)gsrc[j], (las_vp)ldst[j], 16, 0, 0);
            gsrc[j] += 64;
        }
        __syncthreads();
        {
            short8 af[4], bfr[4];
#pragma unroll
            for (int t = 0; t < 4; ++t) {
                af[t] = *(const short8*)(pa[t] + o0);
                bfr[t] = *(const short8*)(pb[t] + o0);
            }
#pragma unroll
            for (int mt = 0; mt < 4; ++mt)
#pragma unroll
                for (int nt = 0; nt < 4; ++nt)
                    acc[mt][nt] = __builtin_amdgcn_mfma_f32_16x16x32_bf16(af[mt], bfr[nt], acc[mt][nt], 0, 0, 0);
#pragma unroll
            for (int t = 0; t < 4; ++t) {
                af[t] = *(const short8*)(pa[t] + o1);
                bfr[t] = *(const short8*)(pb[t] + o1);
            }
#pragma unroll
            for (int mt = 0; mt < 4; ++mt)
#pragma unroll
                for (int nt = 0; nt < 4; ++nt)
                    acc[mt][nt] = __builtin_amdgcn_mfma_f32_16x16x32_bf16(af[mt], bfr[nt], acc[mt][nt], 0, 0, 0);
        }
        __syncthreads();
    }

#pragma unroll
    for (int mt = 0; mt < 4; ++mt) {
#pragma unroll
        for (int nt = 0; nt < 4; ++nt) {
            const int gcol = bn0 + wn + nt * 16 + fr;
#pragma unroll
            for (int r = 0; r < 4; ++r) {
                const int grow = bm0 + wm + mt * 16 + fq * 4 + r;
                if (grow < M) {
                    float v = acc[mt][nt][r];
                    if (OMODE != 0 && OMODE != 8) v += bias[gcol];
                    if (OMODE == 0 || OMODE == 1) {
                        ((BF16*)Cout)[(size_t)grow * N + gcol] = f2bf(v);
                    } else if (OMODE == 2) {
                        int t8 = grow & 7;
                        int rr = (grow >> 3) * 16 + 8 + t8;
                        float w8 = (t8 < 4) ? 0.5f : 0.25f;
                        BF16* R = (BF16*)Cout;
                        size_t o = (size_t)rr * 768 + gcol;
                        R[o] = f2bf(0.5f * bf2f(R[o]) + w8 * v);
                    } else if (OMODE == 3) {
                        int t4 = grow & 3;
                        int rr = (grow >> 2) * 16 + 12 + t4;
                        BF16* R = (BF16*)Cout;
                        size_t o = (size_t)rr * 768 + gcol;
                        R[o] = f2bf(bf2f(R[o]) + 0.25f * v);
                    } else if (OMODE == 4) {
                        int b = grow / 3136;
                        size_t xrow = (size_t)b * 3137 + 1 + (grow - b * 3136);
                        ((float*)Cout)[xrow * 768 + gcol] =
                            v + ((const float*)res)[xrow * 768 + gcol];
                    } else if (OMODE == 6) {
                        // fast GELU: x*sigmoid(2*0.7978845608*(x+0.044715x^3))
                        float u = v * (0.7978845608f + 0.0356774081f * v * v);
                        v = v / (1.0f + __expf(-2.0f * u));
                        ((BF16*)Cout)[(size_t)grow * N + gcol] = f2bf(v);
                    } else {  // 7, 8
                        v += ((const float*)res)[(size_t)grow * N + gcol];
                        ((float*)Cout)[(size_t)grow * N + gcol] = v;
                    }
                }
            }
        }
    }
}

template <int AMAP, int OMODE>
__global__ __launch_bounds__(256) void gemm_bf16(const BF16* __restrict__ A,
                                                 const BF16* __restrict__ Bt,
                                                 const float* __restrict__ bias,
                                                 const void* res,
                                                 void* Cout,
                                                 int M, int N, int K) {
    __shared__ BF16 Al[128 * 64];
    __shared__ BF16 Bl[128 * 64];
    const int gx = gridDim.x;
    const int nwg = gx * (int)gridDim.y;
    const int orig = (int)blockIdx.y * gx + (int)blockIdx.x;
    gemm_body<AMAP, OMODE>(Al, Bl, orig, nwg, gx, A, Bt, bias, res, Cout, M, N, K);
}

// Two independent GEMM jobs in one dispatch (block-uniform branch, shared LDS).
// Job-local XCD swizzle: physical XCD of job-1 blocks is a constant mod-8
// shift of the computed one — chunking/bijectivity preserved.
template <int AMAP0, int OMODE0, int AMAP1, int OMODE1>
__global__ __launch_bounds__(256) void gemm_dual(
        int nblk0, int gx0,
        const BF16* A0, const BF16* B0, const float* b0, const void* r0, void* C0,
        int M0, int N0, int K0,
        int gx1,
        const BF16* A1, const BF16* B1, const float* b1, const void* r1, void* C1,
        int M1, int N1, int K1) {
    __shared__ BF16 Al[128 * 64];
    __shared__ BF16 Bl[128 * 64];
    const int bid = blockIdx.x;
    if (bid < nblk0)
        gemm_body<AMAP0, OMODE0>(Al, Bl, bid, nblk0, gx0, A0, B0, b0, r0, C0, M0, N0, K0);
    else
        gemm_body<AMAP1, OMODE1>(Al, Bl, bid - nblk0, (int)gridDim.x - nblk0, gx1,
                                 A1, B1, b1, r1, C1, M1, N1, K1);
}

// ---------------------------------------------------------------------------
// Temporal attention, one block per (group, head). L in {4,8,16}, d=64.
// ---------------------------------------------------------------------------
template <int L, int NT>
__global__ __launch_bounds__(NT) void temporal_attn(const BF16* __restrict__ qkv,
                                                    BF16* __restrict__ outp) {
    __shared__ float q[L * 64];
    __shared__ float k[L * 65];
    __shared__ float v[L * 64];
    __shared__ float S[L * L];
    const int bh = blockIdx.x;
    const int b = bh / 12, h = bh % 12;
    const int tid = threadIdx.x;
    const size_t rb = (size_t)b * L;
    for (int idx = tid; idx < L * 64; idx += NT) {
        int i = idx >> 6, d = idx & 63;
        size_t base = (rb + i) * 2304 + h * 64 + d;
        q[i * 64 + d] = bf2f(qkv[base]);
        k[i * 65 + d] = bf2f(qkv[base + 768]);
        v[i * 64 + d] = bf2f(qkv[base + 1536]);
    }
    __syncthreads();
    for (int idx = tid; idx < L * L; idx += NT) {
        int i = idx / L, j = idx % L;
        float a = 0.f;
#pragma unroll
        for (int d = 0; d < 64; ++d) a += q[i * 64 + d] * k[j * 65 + d];
        S[idx] = a * 0.125f;
    }
    __syncthreads();
    if (tid < L) {
        float mx = -1e30f;
        for (int j = 0; j < L; ++j) mx = fmaxf(mx, S[tid * L + j]);
        float sm = 0.f;
        for (int j = 0; j < L; ++j) { float e = __expf(S[tid * L + j] - mx); S[tid * L + j] = e; sm += e; }
        float inv = 1.0f / sm;
        for (int j = 0; j < L; ++j) S[tid * L + j] *= inv;
    }
    __syncthreads();
    for (int idx = tid; idx < L * 64; idx += NT) {
        int i = idx >> 6, d = idx & 63;
        float acc = 0.f;
#pragma unroll
        for (int j = 0; j < L; ++j) acc += S[i * L + j] * v[j * 64 + d];
        outp[(rb + i) * 768 + h * 64 + d] = f2bf(acc);
    }
}

// ---------------------------------------------------------------------------
// MFMA spatial attention. Block = (bt, h, qtile-of-64); 4 waves x 16 queries.
// Pl aliases Ks (Ks dead after QK^T; barrier guards the overlap) -> LDS
// 90KB -> 59.6KB -> 2 blocks/CU.
// ---------------------------------------------------------------------------
__global__ __launch_bounds__(256) void spatial_attn_mfma(const BF16* __restrict__ qkv,
                                                         BF16* __restrict__ outp) {
    const int bid = blockIdx.x;
    const int qt = bid & 3;
    const int h = (bid >> 2) % 12;
    const int bt = bid / 48;
    const int rowbase = bt * 197;
    __shared__ BF16 KsPl[208 * 72];   // Ks during QK^T; Pl (4 x 16*232) during PV
    __shared__ BF16 Vt[64 * 232];
    const int tid = threadIdx.x;
    const int lane = tid & 63;
    const int w = tid >> 6;
    const int ln = lane & 15;
    const int quad = lane >> 4;

    for (int it = tid; it < 208 * 8; it += 256) {
        int key = it >> 3, c = it & 7;
        int kc = key < 197 ? key : 196;
        short8 gk = *(const short8*)(qkv + (size_t)(rowbase + kc) * 2304 + 768 + h * 64 + c * 8);
        *(short8*)&KsPl[key * 72 + c * 8] = gk;
    }
    for (int it = tid; it < 112 * 8; it += 256) {
        int p = it >> 3, c = it & 7;
        int kc0 = (2 * p < 197) ? 2 * p : 196;
        int kc1 = (2 * p + 1 < 197) ? 2 * p + 1 : 196;
        short8 a = *(const short8*)(qkv + (size_t)(rowbase + kc0) * 2304 + 1536 + h * 64 + c * 8);
        short8 b = *(const short8*)(qkv + (size_t)(rowbase + kc1) * 2304 + 1536 + h * 64 + c * 8);
#pragma unroll
        for (int e = 0; e < 8; ++e) {
            short2v pr;
            pr[0] = a[e];
            pr[1] = b[e];
            *(short2v*)&Vt[(c * 8 + e) * 232 + 2 * p] = pr;
        }
    }
    __syncthreads();

    const int m0 = qt * 64 + w * 16;
    int qrow = m0 + ln; if (qrow > 196) qrow = 196;
    const BF16* qptr = qkv + (size_t)(rowbase + qrow) * 2304 + h * 64 + quad * 8;
    short8 aq0 = *(const short8*)(qptr);
    short8 aq1 = *(const short8*)(qptr + 32);

    floatx4 sacc[13];
#pragma unroll
    for (int nt = 0; nt < 13; ++nt) sacc[nt] = (floatx4){0.f, 0.f, 0.f, 0.f};
#pragma unroll
    for (int nt = 0; nt < 13; ++nt) {
        const BF16* kb = &KsPl[(nt * 16 + ln) * 72 + quad * 8];
        short8 b0 = *(const short8*)kb;
        short8 b1 = *(const short8*)(kb + 32);
        sacc[nt] = __builtin_amdgcn_mfma_f32_16x16x32_bf16(aq0, b0, sacc[nt], 0, 0, 0);
        sacc[nt] = __builtin_amdgcn_mfma_f32_16x16x32_bf16(aq1, b1, sacc[nt], 0, 0, 0);
    }
    __syncthreads();   // all waves done reading Ks before Pl overwrites it

#pragma unroll
    for (int r = 0; r < 4; ++r) {
        float mx = -1e30f;
#pragma unroll
        for (int nt = 0; nt < 13; ++nt) {
            float s = sacc[nt][r] * 0.125f;
            sacc[nt][r] = s;
            if (nt * 16 + ln < 197) mx = fmaxf(mx, s);
        }
        mx = fmaxf(mx, __shfl_xor(mx, 1));
        mx = fmaxf(mx, __shfl_xor(mx, 2));
        mx = fmaxf(mx, __shfl_xor(mx, 4));
        mx = fmaxf(mx, __shfl_xor(mx, 8));
        float sum = 0.f;
#pragma unroll
        for (int nt = 0; nt < 13; ++nt) {
            float e = (nt * 16 + ln < 197) ? __expf(sacc[nt][r] - mx) : 0.f;
            sacc[nt][r] = e;
            sum += e;
        }
        sum += __shfl_xor(sum, 1);
        sum += __shfl_xor(sum, 2);
        sum += __shfl_xor(sum, 4);
        sum += __shfl_xor(sum, 8);
        float inv = 1.0f / sum;
#pragma unroll
        for (int nt = 0; nt < 13; ++nt) sacc[nt][r] *= inv;
    }

    BF16* pw = KsPl + w * (16 * 232);
#pragma unroll
    for (int nt = 0; nt < 13; ++nt)
#pragma unroll
        for (int r = 0; r < 4; ++r)
            pw[(quad * 4 + r) * 232 + nt * 16 + ln] = f2bf(sacc[nt][r]);
#pragma unroll
    for (int r = 0; r < 4; ++r)
        pw[(quad * 4 + r) * 232 + 208 + ln] = f2bf(0.f);

    floatx4 oacc[4];
#pragma unroll
    for (int nt = 0; nt < 4; ++nt) oacc[nt] = (floatx4){0.f, 0.f, 0.f, 0.f};
    for (int kb = 0; kb < 7; ++kb) {
        short8 ap = *(const short8*)&pw[ln * 232 + kb * 32 + quad * 8];
#pragma unroll
        for (int nt = 0; nt < 4; ++nt) {
            short8 bv = *(const short8*)&Vt[(nt * 16 + ln) * 232 + kb * 32 + quad * 8];
            oacc[nt] = __builtin_amdgcn_mfma_f32_16x16x32_bf16(ap, bv, oacc[nt], 0, 0, 0);
        }
    }

#pragma unroll
    for (int nt = 0; nt < 4; ++nt) {
        int dim = nt * 16 + ln;
#pragma unroll
        for (int r = 0; r < 4; ++r) {
            int q = m0 + quad * 4 + r;
            if (q < 197)
                outp[(size_t)(rowbase + q) * 768 + h * 64 + dim] = f2bf(oacc[nt][r]);
        }
    }
}

// ---------------------------------------------------------------------------
// Fused cls path: LN (lncls) of the 16 cls rows of batch b into LDS, then the
// tiny second attention.
// ---------------------------------------------------------------------------
__global__ __launch_bounds__(256) void cls_ln_attn_kernel(const BF16* __restrict__ res_sp,
                                                          const float* __restrict__ g,
                                                          const float* __restrict__ bta,
                                                          float* __restrict__ clsout) {
    const int b = blockIdx.x;  // 0..3
    const int tid = threadIdx.x;
    __shared__ float sLN[16][768];
    __shared__ float red[8];
    __shared__ float dots[16];
    __shared__ float aw[16];

    for (int t = 0; t < 16; ++t) {
        const BF16* src = res_sp + (size_t)((b * 16 + t) * 197) * 768;
        float x0 = bf2f(src[tid]);
        float x1 = bf2f(src[tid + 256]);
        float x2 = bf2f(src[tid + 512]);
        float s = x0 + x1 + x2;
        float ss = x0 * x0 + x1 * x1 + x2 * x2;
#pragma unroll
        for (int o = 32; o > 0; o >>= 1) { s += __shfl_down(s, o); ss += __shfl_down(ss, o); }
        if ((tid & 63) == 0) { red[tid >> 6] = s; red[4 + (tid >> 6)] = ss; }
        __syncthreads();
        s = red[0] + red[1] + red[2] + red[3];
        ss = red[4] + red[5] + red[6] + red[7];
        const float mu = s * (1.0f / 768.0f);
        const float var = ss * (1.0f / 768.0f) - mu * mu;
        const float rstd = rsqrtf(var + 1e-5f);
        sLN[t][tid]       = (x0 - mu) * rstd * g[tid] + bta[tid];
        sLN[t][tid + 256] = (x1 - mu) * rstd * g[tid + 256] + bta[tid + 256];
        sLN[t][tid + 512] = (x2 - mu) * rstd * g[tid + 512] + bta[tid + 512];
        __syncthreads();
    }

    const int t = tid >> 4, l16 = tid & 15;
    float p = 0.f;
    for (int c = l16; c < 768; c += 16) p += sLN[15][c] * sLN[t][c];
#pragma unroll
    for (int o = 8; o > 0; o >>= 1) p += __shfl_down(p, o, 16);
    if (l16 == 0) dots[t] = p;
    __syncthreads();
    if (tid == 0) {
        float mx = -1e30f;
        for (int j = 0; j < 16; ++j) mx = fmaxf(mx, dots[j]);
        float s = 0.f;
        for (int j = 0; j < 16; ++j) { aw[j] = __expf(dots[j] - mx); s += aw[j]; }
        float inv = 1.0f / s;
        for (int j = 0; j < 16; ++j) aw[j] *= inv;
    }
    __syncthreads();
    for (int c = tid; c < 768; c += 256) {
        float acc = 0.f;
#pragma unroll
        for (int j = 0; j < 16; ++j) acc += aw[j] * sLN[j][c];
        clsout[(size_t)b * 768 + c] = acc;
    }
}

// ---------------------------------------------------------------------------
// Fused x_cat build + ln2.
// ---------------------------------------------------------------------------
__global__ __launch_bounds__(256) void xcat_ln_kernel(const float* __restrict__ x,
                                                      const BF16* __restrict__ res_sp,
                                                      const float* __restrict__ clsout,
                                                      const float* __restrict__ g,
                                                      const float* __restrict__ bta,
                                                      float* outbuf,
                                                      BF16* __restrict__ hln) {
    const int gidx = blockIdx.x;
    const int b = gidx / 3137, j = gidx - b * 3137;
    const int tid = threadIdx.x;
    float v0, v1, v2;
    if (j == 0) {
        const float* xr = x + (size_t)b * 3137 * 768;
        const float* cr = clsout + (size_t)b * 768;
        v0 = xr[tid] + cr[tid];
        v1 = xr[tid + 256] + cr[tid + 256];
        v2 = xr[tid + 512] + cr[tid + 512];
    } else {
        const int p = j - 1, k = p >> 4, t = p & 15;
        const BF16* rs = res_sp + (size_t)((b * 16 + t) * 197 + 1 + k) * 768;
        float* orow = outbuf + (size_t)gidx * 768;
        v0 = orow[tid] + bf2f(rs[tid]);
        v1 = orow[tid + 256] + bf2f(rs[tid + 256]);
        v2 = orow[tid + 512] + bf2f(rs[tid + 512]);
    }
    float* orow = outbuf + (size_t)gidx * 768;
    orow[tid] = v0; orow[tid + 256] = v1; orow[tid + 512] = v2;

    float s = v0 + v1 + v2;
    float ss = v0 * v0 + v1 * v1 + v2 * v2;
    __shared__ float red[8];
#pragma unroll
    for (int o = 32; o > 0; o >>= 1) { s += __shfl_down(s, o); ss += __shfl_down(ss, o); }
    if ((tid & 63) == 0) { red[tid >> 6] = s; red[4 + (tid >> 6)] = ss; }
    __syncthreads();
    s = red[0] + red[1] + red[2] + red[3];
    ss = red[4] + red[5] + red[6] + red[7];
    const float mu = s * (1.0f / 768.0f);
    const float var = ss * (1.0f / 768.0f) - mu * mu;
    const float rstd = rsqrtf(var + 1e-5f);
#pragma unroll
    for (int i = 0; i < 3; ++i) {
        int c = tid + i * 256;
        float xv = (i == 0) ? v0 : (i == 1) ? v1 : v2;
        hln[(size_t)gidx * 768 + c] = f2bf((xv - mu) * rstd * g[c] + bta[c]);
    }
}

// ---------------------------------------------------------------------------
extern "C" void kernel_launch(void* const* d_in, const int* in_sizes, int n_in,
                              void* d_out, int out_size, void* d_ws, size_t ws_size,
                              hipStream_t stream) {
    const float* x       = (const float*)d_in[0];
    const float* ln1_g   = (const float*)d_in[4];
    const float* ln1_b   = (const float*)d_in[5];
    const float* lnt_g   = (const float*)d_in[6];
    const float* lnt_b   = (const float*)d_in[7];
    const float* ln2_g   = (const float*)d_in[8];
    const float* ln2_b   = (const float*)d_in[9];
    const float* lncls_g = (const float*)d_in[10];
    const float* lncls_b = (const float*)d_in[11];
    const float* Wqkv_s  = (const float*)d_in[12];
    const float* Wproj_s = (const float*)d_in[13];
    const float* bproj_s = (const float*)d_in[14];
    const float* Wqkv4   = (const float*)d_in[15];
    const float* Wqkv8   = (const float*)d_in[16];
    const float* Wqkv16  = (const float*)d_in[17];
    const float* Wp4     = (const float*)d_in[18];
    const float* bp4     = (const float*)d_in[19];
    const float* Wp8     = (const float*)d_in[20];
    const float* bp8     = (const float*)d_in[21];
    const float* Wp16    = (const float*)d_in[22];
    const float* bp16    = (const float*)d_in[23];
    const float* Wtfc    = (const float*)d_in[24];
    const float* btfc    = (const float*)d_in[25];
    const float* Wfc1    = (const float*)d_in[26];
    const float* bfc1    = (const float*)d_in[27];
    const float* Wfc2    = (const float*)d_in[28];
    const float* bfc2    = (const float*)d_in[29];
    float* out = (float*)d_out;

    // ---- workspace layout (bytes), lifetime-aliased; base peak = 96,694,272
    const size_t oW0 = 0;
    const size_t oW1 = 4718592;
    const size_t oR1 = 9437184;
    const size_t oR2 = 28803072;
    const size_t oR3 = 48070656;
    const size_t oR4 = 77119488;
    const size_t oCO = 96681984;
    const size_t NEED = 96694272;
    const size_t NEED_BIG = NEED + 29491200;
    if (ws_size < NEED) return;
    char* ws = (char*)d_ws;

    BF16* w0       = (BF16*)(ws + oW0);
    BF16* w1       = (BF16*)(ws + oW1);
    BF16* xtn      = (BF16*)(ws + oR1);
    BF16* atts     = (BF16*)(ws + oR1);
    BF16* hln      = (BF16*)(ws + oR1);
    BF16* res_temp = (BF16*)(ws + oR2);
    BF16* h1       = (BF16*)(ws + oR2);   // 12548x1536 bf16 spans R2+R3 head
    BF16* qkv      = (BF16*)(ws + oR3);
    BF16* att      = (BF16*)(ws + oR4);
    BF16* xsn      = (BF16*)(ws + oR4);
    BF16* res_sp   = (BF16*)(ws + oR4);
    float* clsout  = (float*)(ws + oCO);

    const bool big = (ws_size >= NEED_BIG);
    BF16 *tqkv16, *tqkv8, *tqkv4, *tqkvs, *tp16, *tp8, *tp4, *ttfc, *tproj, *tfc1, *tfc2;
    if (big) {
        char* wx = ws + NEED;
        tqkv16 = (BF16*)wx; wx += 3538944;
        tqkv8  = (BF16*)wx; wx += 3538944;
        tqkv4  = (BF16*)wx; wx += 3538944;
        tqkvs  = (BF16*)wx; wx += 3538944;
        tp16   = (BF16*)wx; wx += 1179648;
        tp8    = (BF16*)wx; wx += 1179648;
        tp4    = (BF16*)wx; wx += 1179648;
        ttfc   = (BF16*)wx; wx += 1179648;
        tproj  = (BF16*)wx; wx += 1179648;
        tfc1   = (BF16*)wx; wx += 4718592;
        tfc2   = (BF16*)wx; wx += 4718592;
        WTParams P;
        P.j[0]  = { Wqkv16,                     tqkv16,                     768, 2304,     0 };
        P.j[1]  = { Wqkv8,                      tqkv8,                      768, 2304,  1728 };
        P.j[2]  = { Wqkv4,                      tqkv4,                      768, 2304,  3456 };
        P.j[3]  = { Wqkv_s,                     tqkvs,                      768, 2304,  5184 };
        P.j[4]  = { Wp16,                       tp16,                       768,  768,  6912 };
        P.j[5]  = { Wp8,                        tp8,                        768,  768,  7488 };
        P.j[6]  = { Wp4,                        tp4,                        768,  768,  8064 };
        P.j[7]  = { Wtfc,                       ttfc,                       768,  768,  8640 };
        P.j[8]  = { Wproj_s,                    tproj,                      768,  768,  9216 };
        P.j[9]  = { Wfc1,                       tfc1,                       768, 3072,  9792 };
        P.j[10] = { Wfc2,                       tfc2,                      1536,  768, 12096 };
        P.j[11] = { Wfc2 + (size_t)1536 * 768,  tfc2 + (size_t)768 * 1536, 1536,  768, 13248 };
        wtrans_all<<<14400, 256, 0, stream>>>(P);
    } else {
        tqkv16 = w0; tqkv8 = w0; tqkv4 = w0; tqkvs = w1;
        tp16 = w1; tp8 = w1; tp4 = w1; ttfc = w0; tproj = w0;
        tfc1 = w0; tfc2 = w1;
    }

    // ---- temporal LN
    ln_kernel<0><<<12544, 256, 0, stream>>>(x, nullptr, nullptr, lnt_g, lnt_b, xtn, nullptr);

    // ---- scale 16 (2 row-chunks of 6272)
    if (!big) wtrans<<<dim3(24, 72), 256, 0, stream>>>(Wqkv16, tqkv16, 768, 2304);
    for (int c = 0; c < 2; ++c) {
        gemm_bf16<0, 0><<<dim3(18, 49), 256, 0, stream>>>(xtn + (size_t)c * 6272 * 768, tqkv16, nullptr, nullptr, qkv, 6272, 2304, 768);
        temporal_attn<16, 256><<<4704, 256, 0, stream>>>(qkv, att + (size_t)c * 6272 * 768);
    }

    // ---- co-launch: p16 (att->res_temp) || qkv8 GEMM (xtn->qkv) — independent
    if (!big) {
        wtrans<<<dim3(24, 24), 256, 0, stream>>>(Wp16, tp16, 768, 768);
        wtrans<<<dim3(24, 72), 256, 0, stream>>>(Wqkv8, tqkv8, 768, 2304);
    }
    gemm_dual<0, 1, 1, 0><<<588 + 882, 256, 0, stream>>>(
        588, 6, att, tp16, bp16, nullptr, res_temp, 12544, 768, 768,
        18, xtn, tqkv8, nullptr, nullptr, qkv, 6272, 2304, 768);
    temporal_attn<8, 64><<<9408, 64, 0, stream>>>(qkv, att);

    // ---- co-launch: p8 (att RMW res_temp) || qkv4 GEMM (xtn->qkv)
    if (!big) {
        wtrans<<<dim3(24, 24), 256, 0, stream>>>(Wp8, tp8, 768, 768);
        wtrans<<<dim3(24, 72), 256, 0, stream>>>(Wqkv4, tqkv4, 768, 2304);
    }
    gemm_dual<0, 2, 2, 0><<<294 + 450, 256, 0, stream>>>(
        294, 6, att, tp8, bp8, nullptr, res_temp, 6272, 768, 768,
        18, xtn, tqkv4, nullptr, nullptr, qkv, 3136, 2304, 768);
    temporal_attn<4, 64><<<9408, 64, 0, stream>>>(qkv, att);

    if (!big) wtrans<<<dim3(24, 24), 256, 0, stream>>>(Wp4, tp4, 768, 768);
    gemm_bf16<0, 3><<<dim3(6, 25), 256, 0, stream>>>(att, tp4, bp4, nullptr, res_temp, 3136, 768, 768);

    // ---- temporal FC + x residual -> xtfull stored in d_out at x-like rows
    if (!big) wtrans<<<dim3(24, 24), 256, 0, stream>>>(Wtfc, ttfc, 768, 768);
    gemm_bf16<0, 4><<<dim3(6, 98), 256, 0, stream>>>(res_temp, ttfc, btfc, x, out, 12544, 768, 768);

    // ---- spatial path (2 chunks of 32 bt-groups = 6304 rows)
    ln_kernel<1><<<12608, 256, 0, stream>>>(x, out, nullptr, ln1_g, ln1_b, xsn, nullptr);
    if (!big) wtrans<<<dim3(24, 72), 256, 0, stream>>>(Wqkv_s, tqkvs, 768, 2304);
    for (int c = 0; c < 2; ++c) {
        gemm_bf16<0, 0><<<dim3(18, 50), 256, 0, stream>>>(xsn + (size_t)c * 6304 * 768, tqkvs, nullptr, nullptr, qkv, 6304, 2304, 768);
        spatial_attn_mfma<<<1536, 256, 0, stream>>>(qkv, atts + (size_t)c * 6304 * 768);
    }
    if (!big) wtrans<<<dim3(24, 24), 256, 0, stream>>>(Wproj_s, tproj, 768, 768);
    gemm_bf16<0, 1><<<dim3(6, 99), 256, 0, stream>>>(atts, tproj, bproj_s, nullptr, res_sp, 12608, 768, 768);

    // ---- cls path (fused LN + attention)
    cls_ln_attn_kernel<<<4, 256, 0, stream>>>(res_sp, lncls_g, lncls_b, clsout);

    // ---- combine + ln2 fused (in-place x_cat in d_out, hln bf16 out)
    xcat_ln_kernel<<<12548, 256, 0, stream>>>(x, res_sp, clsout, ln2_g, ln2_b, out, hln);

    // ---- MLP: full-M, hidden split in 2 halves; fc2 accumulates into d_out
    if (!big) {
        wtrans<<<dim3(24, 96), 256, 0, stream>>>(Wfc1, tfc1, 768, 3072);
        wtrans<<<dim3(48, 24), 256, 0, stream>>>(Wfc2, tfc2, 1536, 768);
        wtrans<<<dim3(48, 24), 256, 0, stream>>>(Wfc2 + (size_t)1536 * 768, tfc2 + (size_t)768 * 1536, 1536, 768);
    }

    // half a
    gemm_bf16<0, 6><<<dim3(12, 99), 256, 0, stream>>>(hln, tfc1, bfc1, nullptr, h1, 12548, 1536, 768);
    gemm_bf16<0, 7><<<dim3(6, 99), 256, 0, stream>>>(h1, tfc2, bfc2, out, out, 12548, 768, 1536);
    // half b
    gemm_bf16<0, 6><<<dim3(12, 99), 256, 0, stream>>>(hln, tfc1 + (size_t)1536 * 768, bfc1 + 1536, nullptr, h1, 12548, 1536, 768);
    gemm_bf16<0, 8><<<dim3(6, 99), 256, 0, stream>>>(h1, tfc2 + (size_t)768 * 1536, nullptr, out, out, 12548, 768, 1536);
}

// Round 10
// 926.736 us; speedup vs baseline: 1.3515x; 1.0170x over previous
//
#include <hip/hip_runtime.h>
#include <hip/hip_bf16.h>
#include <stdint.h>

#define BF16 __hip_bfloat16

typedef __attribute__((ext_vector_type(8))) short short8;
typedef __attribute__((ext_vector_type(2))) short short2v;
typedef __attribute__((ext_vector_type(4))) float floatx4;

typedef const __attribute__((address_space(1))) void* gas_cvp;
typedef __attribute__((address_space(3))) void* las_vp;

__device__ __forceinline__ float bf2f(BF16 v) { return __bfloat162float(v); }
__device__ __forceinline__ BF16 f2bf(float v) { return __float2bfloat16(v); }

// ---------------------------------------------------------------------------
// Weight fp32 [K,N] -> bf16 transposed [N,K]  (single-weight fallback)
// ---------------------------------------------------------------------------
__global__ __launch_bounds__(256) void wtrans(const float* __restrict__ W,
                                              BF16* __restrict__ Wt, int K, int N) {
    __shared__ float t[32][33];
    int k0 = blockIdx.x * 32, n0 = blockIdx.y * 32;
    int tx = threadIdx.x & 31, ty = threadIdx.x >> 5;  // ty 0..7
#pragma unroll
    for (int i = 0; i < 32; i += 8) t[ty + i][tx] = W[(size_t)(k0 + ty + i) * N + n0 + tx];
    __syncthreads();
#pragma unroll
    for (int i = 0; i < 32; i += 8)
        Wt[(size_t)(n0 + ty + i) * K + k0 + tx] = f2bf(t[tx][ty + i]);
}

// ---------------------------------------------------------------------------
// Batched weight transpose: all 12 jobs in one dispatch.
// ---------------------------------------------------------------------------
struct WTJob { const float* src; BF16* dst; int K; int N; int boff; };
struct WTParams { WTJob j[12]; };

__global__ __launch_bounds__(256) void wtrans_all(WTParams P) {
    __shared__ float t[32][33];
    const int bid = blockIdx.x;
    int ji = 0;
#pragma unroll
    for (int i = 1; i < 12; ++i)
        if (bid >= P.j[i].boff) ji = i;
    const float* __restrict__ W = P.j[ji].src;
    BF16* __restrict__ Wt = P.j[ji].dst;
    const int K = P.j[ji].K, N = P.j[ji].N;
    const int lb = bid - P.j[ji].boff;
    const int kb = K >> 5;
    const int k0 = (lb % kb) * 32, n0 = (lb / kb) * 32;
    const int tx = threadIdx.x & 31, ty = threadIdx.x >> 5;
#pragma unroll
    for (int i = 0; i < 32; i += 8) t[ty + i][tx] = W[(size_t)(k0 + ty + i) * N + n0 + tx];
    __syncthreads();
#pragma unroll
    for (int i = 0; i < 32; i += 8)
        Wt[(size_t)(n0 + ty + i) * K + k0 + tx] = f2bf(t[tx][ty + i]);
}

// ---------------------------------------------------------------------------
// LayerNorm over 768 cols, block=256.
// MODE 0: rows of x[:,1:,:]  -> bf16
// MODE 1: spatial xs rows (cls from x fp32 / patch from xtfull-in-dout) -> bf16
// ---------------------------------------------------------------------------
template <int MODE>
__global__ __launch_bounds__(256) void ln_kernel(const float* __restrict__ src0,
                                                 const float* __restrict__ src1,
                                                 const BF16* __restrict__ srcb,
                                                 const float* __restrict__ g,
                                                 const float* __restrict__ bta,
                                                 BF16* __restrict__ dst_bf,
                                                 float* __restrict__ dst_f) {
    const int r = blockIdx.x, tid = threadIdx.x;
    float x0, x1, x2;
    {
        const float* src;
        if (MODE == 0) {
            int b = r / 3136, rr = r - b * 3136;
            src = src0 + ((size_t)b * 3137 + 1 + rr) * 768;
        } else if (MODE == 1) {
            int bt = r / 197, j = r - bt * 197;
            int b = bt >> 4, t = bt & 15;
            if (j == 0) src = src0 + (size_t)b * 3137 * 768;
            else        src = src1 + ((size_t)(b * 3137 + 1) + (size_t)(j - 1) * 16 + t) * 768;
        } else {
            src = src0 + (size_t)r * 768;
        }
        x0 = src[tid]; x1 = src[tid + 256]; x2 = src[tid + 512];
    }
    float s = x0 + x1 + x2;
    float ss = x0 * x0 + x1 * x1 + x2 * x2;
    __shared__ float red[8];
#pragma unroll
    for (int o = 32; o > 0; o >>= 1) { s += __shfl_down(s, o); ss += __shfl_down(ss, o); }
    if ((tid & 63) == 0) { red[tid >> 6] = s; red[4 + (tid >> 6)] = ss; }
    __syncthreads();
    s = red[0] + red[1] + red[2] + red[3];
    ss = red[4] + red[5] + red[6] + red[7];
    const float mu = s * (1.0f / 768.0f);
    const float var = ss * (1.0f / 768.0f) - mu * mu;
    const float rstd = rsqrtf(var + 1e-5f);
#pragma unroll
    for (int i = 0; i < 3; ++i) {
        int c = tid + i * 256;
        float xv = (i == 0) ? x0 : (i == 1) ? x1 : x2;
        float y = (xv - mu) * rstd * g[c] + bta[c];
        dst_bf[(size_t)r * 768 + c] = f2bf(y);
    }
}

// ---------------------------------------------------------------------------
// bf16 GEMM body: C[M,N] = A'[M,K] @ Bt[N,K]^T, row-mapped A, fused epilogue.
// BK=64, XOR-swizzled LDS k-blocks, XCD-chunked bijective block swizzle.
// AMAP: 0 identity; 1 scale8; 2 scale4
// OMODE: 0 bf16; 1 bf16+bias; 2 merge8 RMW; 3 merge4 RMW; 4 fp32+bias+x-res;
//        6 bf16+bias+gelu; 7 fp32+bias+res; 8 fp32+res accumulate
// ---------------------------------------------------------------------------
template <int AMAP, int OMODE>
__device__ __forceinline__ void gemm_body(BF16* Al, BF16* Bl,
                                          int orig, int nwg, int gx,
                                          const BF16* __restrict__ A,
                                          const BF16* __restrict__ Bt,
                                          const float* __restrict__ bias,
                                          const void* res, void* Cout,
                                          int M, int N, int K) {
    const int tid = threadIdx.x;
    const int lane = tid & 63;
    const int w = tid >> 6;

    const int xcd = orig & 7;
    const int idx = orig >> 3;
    const int q8 = nwg >> 3, r8 = nwg & 7;
    const int wgid = (xcd < r8 ? xcd * (q8 + 1) : r8 * (q8 + 1) + (xcd - r8) * q8) + idx;
    const int bn0 = (wgid % gx) * 128;  // N-tile fast-varying: chunk-mates share A
    const int bm0 = (wgid / gx) * 128;

    const BF16* gsrc[8];
    BF16* ldst[8];
    const int rin = lane >> 3;
    const int kblk = (lane & 7) ^ rin;
#pragma unroll
    for (int j = 0; j < 8; ++j) {
        int c = w * 8 + j;
        if (c < 16) {
            int gr = bm0 + c * 8 + rin;
            if (gr > M - 1) gr = M - 1;
            if (AMAP == 1) gr = (gr >> 3) * 16 + 8 + (gr & 7);
            if (AMAP == 2) gr = (gr >> 2) * 16 + 12 + (gr & 3);
            gsrc[j] = A + (size_t)gr * K + kblk * 8;
            ldst[j] = Al + c * 512;
        } else {
            int gn = bn0 + (c - 16) * 8 + rin;
            gsrc[j] = Bt + (size_t)gn * K + kblk * 8;
            ldst[j] = Bl + (c - 16) * 512;
        }
    }

    const int wm = (w & 1) * 64;
    const int wn = (w >> 1) * 64;
    const int fr = lane & 15;
    const int fq = lane >> 4;
    const int sw = fr & 7;
    const int o0 = (fq ^ sw) * 8;
    const int o1 = ((fq + 4) ^ sw) * 8;
    const BF16* pa[4];
    const BF16* pb[4];
#pragma unroll
    for (int t = 0; t < 4; ++t) {
        pa[t] = Al + (wm + t * 16 + fr) * 64;
        pb[t] = Bl + (wn + t * 16 + fr) * 64;
    }

    floatx4 acc[4][4];
#pragma unroll
    for (int i = 0; i < 4; ++i)
#pragma unroll
        for (int j = 0; j < 4; ++j) acc[i][j] = (floatx4){0.f, 0.f, 0.f, 0.f};

    for (int k0 = 0; k0 < K; k0 += 64) {
#pragma unroll
        for (int j = 0; j < 8; ++j) {
            __builtin_amdgcn_global_load_lds((gas_cvp)gsrc[j], (las_vp)ldst[j], 16, 0, 0);
            gsrc[j] += 64;
        }
        __syncthreads();
        {
            short8 af[4], bfr[4];
#pragma unroll
            for (int t = 0; t < 4; ++t) {
                af[t] = *(const short8*)(pa[t] + o0);
                bfr[t] = *(const short8*)(pb[t] + o0);
            }
#pragma unroll
            for (int mt = 0; mt < 4; ++mt)
#pragma unroll
                for (int nt = 0; nt < 4; ++nt)
                    acc[mt][nt] = __builtin_amdgcn_mfma_f32_16x16x32_bf16(af[mt], bfr[nt], acc[mt][nt], 0, 0, 0);
#pragma unroll
            for (int t = 0; t < 4; ++t) {
                af[t] = *(const short8*)(pa[t] + o1);
                bfr[t] = *(const short8*)(pb[t] + o1);
            }
#pragma unroll
            for (int mt = 0; mt < 4; ++mt)
#pragma unroll
                for (int nt = 0; nt < 4; ++nt)
                    acc[mt][nt] = __builtin_amdgcn_mfma_f32_16x16x32_bf16(af[mt], bfr[nt], acc[mt][nt], 0, 0, 0);
        }
        __syncthreads();
    }

#pragma unroll
    for (int mt = 0; mt < 4; ++mt) {
#pragma unroll
        for (int nt = 0; nt < 4; ++nt) {
            const int gcol = bn0 + wn + nt * 16 + fr;
#pragma unroll
            for (int r = 0; r < 4; ++r) {
                const int grow = bm0 + wm + mt * 16 + fq * 4 + r;
                if (grow < M) {
                    float v = acc[mt][nt][r];
                    if (OMODE != 0 && OMODE != 8) v += bias[gcol];
                    if (OMODE == 0 || OMODE == 1) {
                        ((BF16*)Cout)[(size_t)grow * N + gcol] = f2bf(v);
                    } else if (OMODE == 2) {
                        int t8 = grow & 7;
                        int rr = (grow >> 3) * 16 + 8 + t8;
                        float w8 = (t8 < 4) ? 0.5f : 0.25f;
                        BF16* R = (BF16*)Cout;
                        size_t o = (size_t)rr * 768 + gcol;
                        R[o] = f2bf(0.5f * bf2f(R[o]) + w8 * v);
                    } else if (OMODE == 3) {
                        int t4 = grow & 3;
                        int rr = (grow >> 2) * 16 + 12 + t4;
                        BF16* R = (BF16*)Cout;
                        size_t o = (size_t)rr * 768 + gcol;
                        R[o] = f2bf(bf2f(R[o]) + 0.25f * v);
                    } else if (OMODE == 4) {
                        int b = grow / 3136;
                        size_t xrow = (size_t)b * 3137 + 1 + (grow - b * 3136);
                        ((float*)Cout)[xrow * 768 + gcol] =
                            v + ((const float*)res)[xrow * 768 + gcol];
                    } else if (OMODE == 6) {
                        // fast GELU: x*sigmoid(2*0.7978845608*(x+0.044715x^3))
                        float u = v * (0.7978845608f + 0.0356774081f * v * v);
                        v = v / (1.0f + __expf(-2.0f * u));
                        ((BF16*)Cout)[(size_t)grow * N + gcol] = f2bf(v);
                    } else {  // 7, 8
                        v += ((const float*)res)[(size_t)grow * N + gcol];
                        ((float*)Cout)[(size_t)grow * N + gcol] = v;
                    }
                }
            }
        }
    }
}

template <int AMAP, int OMODE>
__global__ __launch_bounds__(256) void gemm_bf16(const BF16* __restrict__ A,
                                                 const BF16* __restrict__ Bt,
                                                 const float* __restrict__ bias,
                                                 const void* res,
                                                 void* Cout,
                                                 int M, int N, int K) {
    __shared__ BF16 Al[128 * 64];
    __shared__ BF16 Bl[128 * 64];
    const int gx = gridDim.x;
    const int nwg = gx * (int)gridDim.y;
    const int orig = (int)blockIdx.y * gx + (int)blockIdx.x;
    gemm_body<AMAP, OMODE>(Al, Bl, orig, nwg, gx, A, Bt, bias, res, Cout, M, N, K);
}

// Two independent GEMM jobs in one dispatch (block-uniform branch, shared LDS).
template <int AMAP0, int OMODE0, int AMAP1, int OMODE1>
__global__ __launch_bounds__(256) void gemm_dual(
        int nblk0, int gx0,
        const BF16* A0, const BF16* B0, const float* b0, const void* r0, void* C0,
        int M0, int N0, int K0,
        int gx1,
        const BF16* A1, const BF16* B1, const float* b1, const void* r1, void* C1,
        int M1, int N1, int K1) {
    __shared__ BF16 Al[128 * 64];
    __shared__ BF16 Bl[128 * 64];
    const int bid = blockIdx.x;
    if (bid < nblk0)
        gemm_body<AMAP0, OMODE0>(Al, Bl, bid, nblk0, gx0, A0, B0, b0, r0, C0, M0, N0, K0);
    else
        gemm_body<AMAP1, OMODE1>(Al, Bl, bid - nblk0, (int)gridDim.x - nblk0, gx1,
                                 A1, B1, b1, r1, C1, M1, N1, K1);
}

// ---------------------------------------------------------------------------
// Temporal attention, one block per (group, head). L in {4,8,16}, d=64.
// Vectorized global I/O: short8 (16B/lane) loads for q/k/v and short8 store
// for the output (G13: scalar bf16 loads ~2-2.5x slower).
// ---------------------------------------------------------------------------
template <int L, int NT>
__global__ __launch_bounds__(NT) void temporal_attn(const BF16* __restrict__ qkv,
                                                    BF16* __restrict__ outp) {
    __shared__ float q[L * 64];
    __shared__ float k[L * 65];
    __shared__ float v[L * 64];
    __shared__ float S[L * L];
    const int bh = blockIdx.x;
    const int b = bh / 12, h = bh % 12;
    const int tid = threadIdx.x;
    const size_t rb = (size_t)b * L;
    for (int idx = tid; idx < L * 8; idx += NT) {
        int i = idx >> 3, d8 = (idx & 7) * 8;
        size_t base = (rb + i) * 2304 + h * 64 + d8;
        short8 qv = *(const short8*)(qkv + base);
        short8 kv = *(const short8*)(qkv + base + 768);
        short8 vv = *(const short8*)(qkv + base + 1536);
#pragma unroll
        for (int e = 0; e < 8; ++e) {
            q[i * 64 + d8 + e] = bf2f(((const BF16*)&qv)[e]);
            k[i * 65 + d8 + e] = bf2f(((const BF16*)&kv)[e]);
            v[i * 64 + d8 + e] = bf2f(((const BF16*)&vv)[e]);
        }
    }
    __syncthreads();
    for (int idx = tid; idx < L * L; idx += NT) {
        int i = idx / L, j = idx % L;
        float a = 0.f;
#pragma unroll
        for (int d = 0; d < 64; ++d) a += q[i * 64 + d] * k[j * 65 + d];
        S[idx] = a * 0.125f;
    }
    __syncthreads();
    if (tid < L) {
        float mx = -1e30f;
        for (int j = 0; j < L; ++j) mx = fmaxf(mx, S[tid * L + j]);
        float sm = 0.f;
        for (int j = 0; j < L; ++j) { float e = __expf(S[tid * L + j] - mx); S[tid * L + j] = e; sm += e; }
        float inv = 1.0f / sm;
        for (int j = 0; j < L; ++j) S[tid * L + j] *= inv;
    }
    __syncthreads();
    for (int idx = tid; idx < L * 8; idx += NT) {
        int i = idx >> 3, d8 = (idx & 7) * 8;
        float acc[8];
#pragma unroll
        for (int e = 0; e < 8; ++e) acc[e] = 0.f;
#pragma unroll
        for (int j = 0; j < L; ++j) {
            float sv = S[i * L + j];
#pragma unroll
            for (int e = 0; e < 8; ++e) acc[e] += sv * v[j * 64 + d8 + e];
        }
        short8 ov;
#pragma unroll
        for (int e = 0; e < 8; ++e) ((BF16*)&ov)[e] = f2bf(acc[e]);
        *(short8*)(outp + (rb + i) * 768 + h * 64 + d8) = ov;
    }
}

// ---------------------------------------------------------------------------
// MFMA spatial attention. Block = (bt, h, qtile-of-64); 4 waves x 16 queries.
// Pl aliases Ks (Ks dead after QK^T; barrier guards) -> 59.6KB -> 2 blocks/CU.
// ---------------------------------------------------------------------------
__global__ __launch_bounds__(256) void spatial_attn_mfma(const BF16* __restrict__ qkv,
                                                         BF16* __restrict__ outp) {
    const int bid = blockIdx.x;
    const int qt = bid & 3;
    const int h = (bid >> 2) % 12;
    const int bt = bid / 48;
    const int rowbase = bt * 197;
    __shared__ BF16 KsPl[208 * 72];   // Ks during QK^T; Pl (4 x 16*232) during PV
    __shared__ BF16 Vt[64 * 232];
    const int tid = threadIdx.x;
    const int lane = tid & 63;
    const int w = tid >> 6;
    const int ln = lane & 15;
    const int quad = lane >> 4;

    for (int it = tid; it < 208 * 8; it += 256) {
        int key = it >> 3, c = it & 7;
        int kc = key < 197 ? key : 196;
        short8 gk = *(const short8*)(qkv + (size_t)(rowbase + kc) * 2304 + 768 + h * 64 + c * 8);
        *(short8*)&KsPl[key * 72 + c * 8] = gk;
    }
    for (int it = tid; it < 112 * 8; it += 256) {
        int p = it >> 3, c = it & 7;
        int kc0 = (2 * p < 197) ? 2 * p : 196;
        int kc1 = (2 * p + 1 < 197) ? 2 * p + 1 : 196;
        short8 a = *(const short8*)(qkv + (size_t)(rowbase + kc0) * 2304 + 1536 + h * 64 + c * 8);
        short8 b = *(const short8*)(qkv + (size_t)(rowbase + kc1) * 2304 + 1536 + h * 64 + c * 8);
#pragma unroll
        for (int e = 0; e < 8; ++e) {
            short2v pr;
            pr[0] = a[e];
            pr[1] = b[e];
            *(short2v*)&Vt[(c * 8 + e) * 232 + 2 * p] = pr;
        }
    }
    __syncthreads();

    const int m0 = qt * 64 + w * 16;
    int qrow = m0 + ln; if (qrow > 196) qrow = 196;
    const BF16* qptr = qkv + (size_t)(rowbase + qrow) * 2304 + h * 64 + quad * 8;
    short8 aq0 = *(const short8*)(qptr);
    short8 aq1 = *(const short8*)(qptr + 32);

    floatx4 sacc[13];
#pragma unroll
    for (int nt = 0; nt < 13; ++nt) sacc[nt] = (floatx4){0.f, 0.f, 0.f, 0.f};
#pragma unroll
    for (int nt = 0; nt < 13; ++nt) {
        const BF16* kb = &KsPl[(nt * 16 + ln) * 72 + quad * 8];
        short8 b0 = *(const short8*)kb;
        short8 b1 = *(const short8*)(kb + 32);
        sacc[nt] = __builtin_amdgcn_mfma_f32_16x16x32_bf16(aq0, b0, sacc[nt], 0, 0, 0);
        sacc[nt] = __builtin_amdgcn_mfma_f32_16x16x32_bf16(aq1, b1, sacc[nt], 0, 0, 0);
    }
    __syncthreads();   // all waves done reading Ks before Pl overwrites it

#pragma unroll
    for (int r = 0; r < 4; ++r) {
        float mx = -1e30f;
#pragma unroll
        for (int nt = 0; nt < 13; ++nt) {
            float s = sacc[nt][r] * 0.125f;
            sacc[nt][r] = s;
            if (nt * 16 + ln < 197) mx = fmaxf(mx, s);
        }
        mx = fmaxf(mx, __shfl_xor(mx, 1));
        mx = fmaxf(mx, __shfl_xor(mx, 2));
        mx = fmaxf(mx, __shfl_xor(mx, 4));
        mx = fmaxf(mx, __shfl_xor(mx, 8));
        float sum = 0.f;
#pragma unroll
        for (int nt = 0; nt < 13; ++nt) {
            float e = (nt * 16 + ln < 197) ? __expf(sacc[nt][r] - mx) : 0.f;
            sacc[nt][r] = e;
            sum += e;
        }
        sum += __shfl_xor(sum, 1);
        sum += __shfl_xor(sum, 2);
        sum += __shfl_xor(sum, 4);
        sum += __shfl_xor(sum, 8);
        float inv = 1.0f / sum;
#pragma unroll
        for (int nt = 0; nt < 13; ++nt) sacc[nt][r] *= inv;
    }

    BF16* pw = KsPl + w * (16 * 232);
#pragma unroll
    for (int nt = 0; nt < 13; ++nt)
#pragma unroll
        for (int r = 0; r < 4; ++r)
            pw[(quad * 4 + r) * 232 + nt * 16 + ln] = f2bf(sacc[nt][r]);
#pragma unroll
    for (int r = 0; r < 4; ++r)
        pw[(quad * 4 + r) * 232 + 208 + ln] = f2bf(0.f);

    floatx4 oacc[4];
#pragma unroll
    for (int nt = 0; nt < 4; ++nt) oacc[nt] = (floatx4){0.f, 0.f, 0.f, 0.f};
    for (int kb = 0; kb < 7; ++kb) {
        short8 ap = *(const short8*)&pw[ln * 232 + kb * 32 + quad * 8];
#pragma unroll
        for (int nt = 0; nt < 4; ++nt) {
            short8 bv = *(const short8*)&Vt[(nt * 16 + ln) * 232 + kb * 32 + quad * 8];
            oacc[nt] = __builtin_amdgcn_mfma_f32_16x16x32_bf16(ap, bv, oacc[nt], 0, 0, 0);
        }
    }

#pragma unroll
    for (int nt = 0; nt < 4; ++nt) {
        int dim = nt * 16 + ln;
#pragma unroll
        for (int r = 0; r < 4; ++r) {
            int q = m0 + quad * 4 + r;
            if (q < 197)
                outp[(size_t)(rowbase + q) * 768 + h * 64 + dim] = f2bf(oacc[nt][r]);
        }
    }
}

// ---------------------------------------------------------------------------
// Fused cls path: LN (lncls) of the 16 cls rows of batch b into LDS, then the
// tiny second attention.
// ---------------------------------------------------------------------------
__global__ __launch_bounds__(256) void cls_ln_attn_kernel(const BF16* __restrict__ res_sp,
                                                          const float* __restrict__ g,
                                                          const float* __restrict__ bta,
                                                          float* __restrict__ clsout) {
    const int b = blockIdx.x;  // 0..3
    const int tid = threadIdx.x;
    __shared__ float sLN[16][768];
    __shared__ float red[8];
    __shared__ float dots[16];
    __shared__ float aw[16];

    for (int t = 0; t < 16; ++t) {
        const BF16* src = res_sp + (size_t)((b * 16 + t) * 197) * 768;
        float x0 = bf2f(src[tid]);
        float x1 = bf2f(src[tid + 256]);
        float x2 = bf2f(src[tid + 512]);
        float s = x0 + x1 + x2;
        float ss = x0 * x0 + x1 * x1 + x2 * x2;
#pragma unroll
        for (int o = 32; o > 0; o >>= 1) { s += __shfl_down(s, o); ss += __shfl_down(ss, o); }
        if ((tid & 63) == 0) { red[tid >> 6] = s; red[4 + (tid >> 6)] = ss; }
        __syncthreads();
        s = red[0] + red[1] + red[2] + red[3];
        ss = red[4] + red[5] + red[6] + red[7];
        const float mu = s * (1.0f / 768.0f);
        const float var = ss * (1.0f / 768.0f) - mu * mu;
        const float rstd = rsqrtf(var + 1e-5f);
        sLN[t][tid]       = (x0 - mu) * rstd * g[tid] + bta[tid];
        sLN[t][tid + 256] = (x1 - mu) * rstd * g[tid + 256] + bta[tid + 256];
        sLN[t][tid + 512] = (x2 - mu) * rstd * g[tid + 512] + bta[tid + 512];
        __syncthreads();
    }

    const int t = tid >> 4, l16 = tid & 15;
    float p = 0.f;
    for (int c = l16; c < 768; c += 16) p += sLN[15][c] * sLN[t][c];
#pragma unroll
    for (int o = 8; o > 0; o >>= 1) p += __shfl_down(p, o, 16);
    if (l16 == 0) dots[t] = p;
    __syncthreads();
    if (tid == 0) {
        float mx = -1e30f;
        for (int j = 0; j < 16; ++j) mx = fmaxf(mx, dots[j]);
        float s = 0.f;
        for (int j = 0; j < 16; ++j) { aw[j] = __expf(dots[j] - mx); s += aw[j]; }
        float inv = 1.0f / s;
        for (int j = 0; j < 16; ++j) aw[j] *= inv;
    }
    __syncthreads();
    for (int c = tid; c < 768; c += 256) {
        float acc = 0.f;
#pragma unroll
        for (int j = 0; j < 16; ++j) acc += aw[j] * sLN[j][c];
        clsout[(size_t)b * 768 + c] = acc;
    }
}

// ---------------------------------------------------------------------------
// Fused x_cat build + ln2.
// ---------------------------------------------------------------------------
__global__ __launch_bounds__(256) void xcat_ln_kernel(const float* __restrict__ x,
                                                      const BF16* __restrict__ res_sp,
                                                      const float* __restrict__ clsout,
                                                      const float* __restrict__ g,
                                                      const float* __restrict__ bta,
                                                      float* outbuf,
                                                      BF16* __restrict__ hln) {
    const int gidx = blockIdx.x;
    const int b = gidx / 3137, j = gidx - b * 3137;
    const int tid = threadIdx.x;
    float v0, v1, v2;
    if (j == 0) {
        const float* xr = x + (size_t)b * 3137 * 768;
        const float* cr = clsout + (size_t)b * 768;
        v0 = xr[tid] + cr[tid];
        v1 = xr[tid + 256] + cr[tid + 256];
        v2 = xr[tid + 512] + cr[tid + 512];
    } else {
        const int p = j - 1, k = p >> 4, t = p & 15;
        const BF16* rs = res_sp + (size_t)((b * 16 + t) * 197 + 1 + k) * 768;
        float* orow = outbuf + (size_t)gidx * 768;
        v0 = orow[tid] + bf2f(rs[tid]);
        v1 = orow[tid + 256] + bf2f(rs[tid + 256]);
        v2 = orow[tid + 512] + bf2f(rs[tid + 512]);
    }
    float* orow = outbuf + (size_t)gidx * 768;
    orow[tid] = v0; orow[tid + 256] = v1; orow[tid + 512] = v2;

    float s = v0 + v1 + v2;
    float ss = v0 * v0 + v1 * v1 + v2 * v2;
    __shared__ float red[8];
#pragma unroll
    for (int o = 32; o > 0; o >>= 1) { s += __shfl_down(s, o); ss += __shfl_down(ss, o); }
    if ((tid & 63) == 0) { red[tid >> 6] = s; red[4 + (tid >> 6)] = ss; }
    __syncthreads();
    s = red[0] + red[1] + red[2] + red[3];
    ss = red[4] + red[5] + red[6] + red[7];
    const float mu = s * (1.0f / 768.0f);
    const float var = ss * (1.0f / 768.0f) - mu * mu;
    const float rstd = rsqrtf(var + 1e-5f);
#pragma unroll
    for (int i = 0; i < 3; ++i) {
        int c = tid + i * 256;
        float xv = (i == 0) ? v0 : (i == 1) ? v1 : v2;
        hln[(size_t)gidx * 768 + c] = f2bf((xv - mu) * rstd * g[c] + bta[c]);
    }
}

// ---------------------------------------------------------------------------
extern "C" void kernel_launch(void* const* d_in, const int* in_sizes, int n_in,
                              void* d_out, int out_size, void* d_ws, size_t ws_size,
                              hipStream_t stream) {
    const float* x       = (const float*)d_in[0];
    const float* ln1_g   = (const float*)d_in[4];
    const float* ln1_b   = (const float*)d_in[5];
    const float* lnt_g   = (const float*)d_in[6];
    const float* lnt_b   = (const float*)d_in[7];
    const float* ln2_g   = (const float*)d_in[8];
    const float* ln2_b   = (const float*)d_in[9];
    const float* lncls_g = (const float*)d_in[10];
    const float* lncls_b = (const float*)d_in[11];
    const float* Wqkv_s  = (const float*)d_in[12];
    const float* Wproj_s = (const float*)d_in[13];
    const float* bproj_s = (const float*)d_in[14];
    const float* Wqkv4   = (const float*)d_in[15];
    const float* Wqkv8   = (const float*)d_in[16];
    const float* Wqkv16  = (const float*)d_in[17];
    const float* Wp4     = (const float*)d_in[18];
    const float* bp4     = (const float*)d_in[19];
    const float* Wp8     = (const float*)d_in[20];
    const float* bp8     = (const float*)d_in[21];
    const float* Wp16    = (const float*)d_in[22];
    const float* bp16    = (const float*)d_in[23];
    const float* Wtfc    = (const float*)d_in[24];
    const float* btfc    = (const float*)d_in[25];
    const float* Wfc1    = (const float*)d_in[26];
    const float* bfc1    = (const float*)d_in[27];
    const float* Wfc2    = (const float*)d_in[28];
    const float* bfc2    = (const float*)d_in[29];
    float* out = (float*)d_out;

    // ---- workspace layout (bytes), lifetime-aliased; base peak = 96,694,272
    const size_t oW0 = 0;
    const size_t oW1 = 4718592;
    const size_t oR1 = 9437184;
    const size_t oR2 = 28803072;
    const size_t oR3 = 48070656;
    const size_t oR4 = 77119488;
    const size_t oCO = 96681984;
    const size_t NEED = 96694272;
    const size_t NEED_BIG = NEED + 29491200;           // + resident weights
    const size_t NEED_C   = NEED_BIG + 38547456;       // + h1b (fc2a || fc1b overlap)
    if (ws_size < NEED) return;
    char* ws = (char*)d_ws;

    BF16* w0       = (BF16*)(ws + oW0);
    BF16* w1       = (BF16*)(ws + oW1);
    BF16* xtn      = (BF16*)(ws + oR1);
    BF16* atts     = (BF16*)(ws + oR1);
    BF16* hln      = (BF16*)(ws + oR1);
    BF16* res_temp = (BF16*)(ws + oR2);
    BF16* h1       = (BF16*)(ws + oR2);   // 12548x1536 bf16 spans R2+R3 head
    BF16* qkv      = (BF16*)(ws + oR3);
    BF16* att      = (BF16*)(ws + oR4);
    BF16* xsn      = (BF16*)(ws + oR4);
    BF16* res_sp   = (BF16*)(ws + oR4);
    float* clsout  = (float*)(ws + oCO);

    const bool big = (ws_size >= NEED_BIG);
    const bool featC = (ws_size >= NEED_C);
    BF16* h1b = featC ? (BF16*)(ws + NEED_BIG) : nullptr;
    BF16 *tqkv16, *tqkv8, *tqkv4, *tqkvs, *tp16, *tp8, *tp4, *ttfc, *tproj, *tfc1, *tfc2;
    if (big) {
        char* wx = ws + NEED;
        tqkv16 = (BF16*)wx; wx += 3538944;
        tqkv8  = (BF16*)wx; wx += 3538944;
        tqkv4  = (BF16*)wx; wx += 3538944;
        tqkvs  = (BF16*)wx; wx += 3538944;
        tp16   = (BF16*)wx; wx += 1179648;
        tp8    = (BF16*)wx; wx += 1179648;
        tp4    = (BF16*)wx; wx += 1179648;
        ttfc   = (BF16*)wx; wx += 1179648;
        tproj  = (BF16*)wx; wx += 1179648;
        tfc1   = (BF16*)wx; wx += 4718592;
        tfc2   = (BF16*)wx; wx += 4718592;
        WTParams P;
        P.j[0]  = { Wqkv16,                     tqkv16,                     768, 2304,     0 };
        P.j[1]  = { Wqkv8,                      tqkv8,                      768, 2304,  1728 };
        P.j[2]  = { Wqkv4,                      tqkv4,                      768, 2304,  3456 };
        P.j[3]  = { Wqkv_s,                     tqkvs,                      768, 2304,  5184 };
        P.j[4]  = { Wp16,                       tp16,                       768,  768,  6912 };
        P.j[5]  = { Wp8,                        tp8,                        768,  768,  7488 };
        P.j[6]  = { Wp4,                        tp4,                        768,  768,  8064 };
        P.j[7]  = { Wtfc,                       ttfc,                       768,  768,  8640 };
        P.j[8]  = { Wproj_s,                    tproj,                      768,  768,  9216 };
        P.j[9]  = { Wfc1,                       tfc1,                       768, 3072,  9792 };
        P.j[10] = { Wfc2,                       tfc2,                      1536,  768, 12096 };
        P.j[11] = { Wfc2 + (size_t)1536 * 768,  tfc2 + (size_t)768 * 1536, 1536,  768, 13248 };
        wtrans_all<<<14400, 256, 0, stream>>>(P);
    } else {
        tqkv16 = w0; tqkv8 = w0; tqkv4 = w0; tqkvs = w1;
        tp16 = w1; tp8 = w1; tp4 = w1; ttfc = w0; tproj = w0;
        tfc1 = w0; tfc2 = w1;
    }

    // ---- temporal LN
    ln_kernel<0><<<12544, 256, 0, stream>>>(x, nullptr, nullptr, lnt_g, lnt_b, xtn, nullptr);

    // ---- scale 16 (2 row-chunks of 6272)
    if (!big) wtrans<<<dim3(24, 72), 256, 0, stream>>>(Wqkv16, tqkv16, 768, 2304);
    for (int c = 0; c < 2; ++c) {
        gemm_bf16<0, 0><<<dim3(18, 49), 256, 0, stream>>>(xtn + (size_t)c * 6272 * 768, tqkv16, nullptr, nullptr, qkv, 6272, 2304, 768);
        temporal_attn<16, 256><<<4704, 256, 0, stream>>>(qkv, att + (size_t)c * 6272 * 768);
    }

    // ---- co-launch: p16 (att->res_temp) || qkv8 GEMM (xtn->qkv) — independent
    if (!big) {
        wtrans<<<dim3(24, 24), 256, 0, stream>>>(Wp16, tp16, 768, 768);
        wtrans<<<dim3(24, 72), 256, 0, stream>>>(Wqkv8, tqkv8, 768, 2304);
    }
    gemm_dual<0, 1, 1, 0><<<588 + 882, 256, 0, stream>>>(
        588, 6, att, tp16, bp16, nullptr, res_temp, 12544, 768, 768,
        18, xtn, tqkv8, nullptr, nullptr, qkv, 6272, 2304, 768);
    temporal_attn<8, 64><<<9408, 64, 0, stream>>>(qkv, att);

    // ---- co-launch: p8 (att RMW res_temp) || qkv4 GEMM (xtn->qkv)
    if (!big) {
        wtrans<<<dim3(24, 24), 256, 0, stream>>>(Wp8, tp8, 768, 768);
        wtrans<<<dim3(24, 72), 256, 0, stream>>>(Wqkv4, tqkv4, 768, 2304);
    }
    gemm_dual<0, 2, 2, 0><<<294 + 450, 256, 0, stream>>>(
        294, 6, att, tp8, bp8, nullptr, res_temp, 6272, 768, 768,
        18, xtn, tqkv4, nullptr, nullptr, qkv, 3136, 2304, 768);
    temporal_attn<4, 64><<<9408, 64, 0, stream>>>(qkv, att);

    if (!big) wtrans<<<dim3(24, 24), 256, 0, stream>>>(Wp4, tp4, 768, 768);
    gemm_bf16<0, 3><<<dim3(6, 25), 256, 0, stream>>>(att, tp4, bp4, nullptr, res_temp, 3136, 768, 768);

    // ---- temporal FC + x residual -> xtfull stored in d_out at x-like rows
    if (!big) wtrans<<<dim3(24, 24), 256, 0, stream>>>(Wtfc, ttfc, 768, 768);
    gemm_bf16<0, 4><<<dim3(6, 98), 256, 0, stream>>>(res_temp, ttfc, btfc, x, out, 12544, 768, 768);

    // ---- spatial path (2 chunks of 32 bt-groups = 6304 rows)
    ln_kernel<1><<<12608, 256, 0, stream>>>(x, out, nullptr, ln1_g, ln1_b, xsn, nullptr);
    if (!big) wtrans<<<dim3(24, 72), 256, 0, stream>>>(Wqkv_s, tqkvs, 768, 2304);
    for (int c = 0; c < 2; ++c) {
        gemm_bf16<0, 0><<<dim3(18, 50), 256, 0, stream>>>(xsn + (size_t)c * 6304 * 768, tqkvs, nullptr, nullptr, qkv, 6304, 2304, 768);
        spatial_attn_mfma<<<1536, 256, 0, stream>>>(qkv, atts + (size_t)c * 6304 * 768);
    }
    if (!big) wtrans<<<dim3(24, 24), 256, 0, stream>>>(Wproj_s, tproj, 768, 768);
    gemm_bf16<0, 1><<<dim3(6, 99), 256, 0, stream>>>(atts, tproj, bproj_s, nullptr, res_sp, 12608, 768, 768);

    // ---- cls path (fused LN + attention)
    cls_ln_attn_kernel<<<4, 256, 0, stream>>>(res_sp, lncls_g, lncls_b, clsout);

    // ---- combine + ln2 fused (in-place x_cat in d_out, hln bf16 out)
    xcat_ln_kernel<<<12548, 256, 0, stream>>>(x, res_sp, clsout, ln2_g, ln2_b, out, hln);

    // ---- MLP: full-M, hidden split in 2 halves; fc2 accumulates into d_out
    if (!big) {
        wtrans<<<dim3(24, 96), 256, 0, stream>>>(Wfc1, tfc1, 768, 3072);
        wtrans<<<dim3(48, 24), 256, 0, stream>>>(Wfc2, tfc2, 1536, 768);
        wtrans<<<dim3(48, 24), 256, 0, stream>>>(Wfc2 + (size_t)1536 * 768, tfc2 + (size_t)768 * 1536, 1536, 768);
    }

    if (featC) {
        // fc1a -> [fc2a || fc1b] -> fc2b  (h1b decouples the halves)
        gemm_bf16<0, 6><<<dim3(12, 99), 256, 0, stream>>>(hln, tfc1, bfc1, nullptr, h1, 12548, 1536, 768);
        gemm_dual<0, 7, 0, 6><<<594 + 1188, 256, 0, stream>>>(
            594, 6, h1, tfc2, bfc2, out, out, 12548, 768, 1536,
            12, hln, tfc1 + (size_t)1536 * 768, bfc1 + 1536, nullptr, h1b, 12548, 1536, 768);
        gemm_bf16<0, 8><<<dim3(6, 99), 256, 0, stream>>>(h1b, tfc2 + (size_t)768 * 1536, nullptr, out, out, 12548, 768, 1536);
    } else {
        // half a
        gemm_bf16<0, 6><<<dim3(12, 99), 256, 0, stream>>>(hln, tfc1, bfc1, nullptr, h1, 12548, 1536, 768);
        gemm_bf16<0, 7><<<dim3(6, 99), 256, 0, stream>>>(h1, tfc2, bfc2, out, out, 12548, 768, 1536);
        // half b
        gemm_bf16<0, 6><<<dim3(12, 99), 256, 0, stream>>>(hln, tfc1 + (size_t)1536 * 768, bfc1 + 1536, nullptr, h1, 12548, 1536, 768);
        gemm_bf16<0, 8><<<dim3(6, 99), 256, 0, stream>>>(h1, tfc2 + (size_t)768 * 1536, nullptr, out, out, 12548, 768, 1536);
    }
}